// Round 4
// baseline (622.816 us; speedup 1.0000x reference)
//
#include <hip/hip_runtime.h>
#include <math.h>

#define NTHR 1024
#define CAP 8192
#define BINS 4096
#define SMALL 1024
#define GUARD 16u
#define SS 4096
#define NS 4
#define ATHR 256

#define RMAX_F 0.9999999403953552f
#define RMAX_LOG_F -5.960464477539063e-08f
#define NEG_BIG -3.0e38f

typedef unsigned long long ull;

__device__ __forceinline__ unsigned keyOf(float v) {
    unsigned b = __float_as_uint(v);
    return (b & 0x80000000u) ? ~b : (b | 0x80000000u);
}
__device__ __forceinline__ float valOfKey(unsigned k) {
    unsigned b = (k & 0x80000000u) ? (k ^ 0x80000000u) : ~k;
    return __uint_as_float(b);
}
__device__ __forceinline__ ull shflXor64(ull v, int m) {
    int lo = __shfl_xor((int)(unsigned)v, m);
    int hi = __shfl_xor((int)(unsigned)(v >> 32), m);
    return ((ull)(unsigned)hi << 32) | (unsigned)lo;
}

// ---------------------------------------------------------------------------
// R4: 3-stage stream pipeline (diagnostic split front/tail + latency attack).
//  A0 (256 x 1024): subsample -> per-row speculative threshold tlo -> ws;
//      zero per-row counter. Same sample positions / target rule as R3 P0.
//  A1 (1024 x 256): barrier-free compaction of the full row, 4 slices/row,
//      per-thread global atomicAdd append (wave-aggregated by compiler).
//      Candidate SET identical to R3 P1; order differs (sort makes it moot).
//  B  (256 x 1024): tail = R3 verbatim. Prefix: load candidates from ws when
//      count in [k, CAP]; else rebuild everything in-kernel (R3 front end,
//      exact) -> correctness independent of speculation/ws.
//  Host: if ws_size too small, launch B alone in use_ws=0 mode (monolithic).
// ---------------------------------------------------------------------------

#define H4(v4) do { \
        atomicAdd(&hist[((keyOf((v4).x) >> 20) << 1) | cpy], 1u); \
        atomicAdd(&hist[((keyOf((v4).y) >> 20) << 1) | cpy], 1u); \
        atomicAdd(&hist[((keyOf((v4).z) >> 20) << 1) | cpy], 1u); \
        atomicAdd(&hist[((keyOf((v4).w) >> 20) << 1) | cpy], 1u); \
    } while (0)

// ---------------- A0: threshold + counter reset ----------------------------
__global__ __launch_bounds__(NTHR) void a0_thresh(
    const float* __restrict__ logits,
    const int* __restrict__ top_kv,
    int* __restrict__ ws_cnt,
    unsigned* __restrict__ ws_tlo,
    int B, int V)
{
    const int r = blockIdx.x;
    const int tid = threadIdx.x;
    const int lane = tid & 63;
    const int wid = tid >> 6;
    __shared__ unsigned hist[BINS * 2];
    __shared__ int wtotI[16];
    __shared__ unsigned s_prefix;

    const float* row = logits + (long long)r * V;
    const float4* row4 = (const float4*)row;
    const int V4 = V >> 2;
    const unsigned cpy = tid & 1u;

    int k = top_kv[r];
    if (k < 1) k = 1;
    if (k > V) k = V;

    for (int i = tid; i < BINS * 2; i += NTHR) hist[i] = 0;
    __syncthreads();
    {
        int f4pos = (int)(((long long)tid * V4) >> 10);   // 4096 spread samples
        float4 sv = row4[f4pos];
        H4(sv);
    }
    __syncthreads();
    int ts;
    {
        int tc = 2 * k + 400;
        if (tc > 2400) tc = 2400;
        if (tc < 600) tc = 600;
        ts = (int)(((long long)tc * SS + V - 1) / V);
        if (ts < 4) ts = 4;
    }
    {
        int base = tid << 2;
        int cs = 0;
        #pragma unroll
        for (int j = 0; j < 4; ++j)
            cs += (int)(hist[(base + j) * 2] + hist[(base + j) * 2 + 1]);
        int vv = cs;
        #pragma unroll
        for (int d = 1; d < 64; d <<= 1) {
            int o = __shfl_down(vv, d);
            if (lane + d < 64) vv += o;
        }
        if (lane == 0) wtotI[wid] = vv;
        __syncthreads();
        int off = 0;
        for (int w = wid + 1; w < 16; ++w) off += wtotI[w];
        int mine = vv + off;
        int above = mine - cs;
        if (mine >= ts && above < ts) {                   // exactly one thread
            int run = above;
            for (int b = base + 3; b >= base; --b) {
                int mb = (int)(hist[b * 2] + hist[b * 2 + 1]);
                if (run + mb >= ts) { s_prefix = (unsigned)b; break; }
                run += mb;
            }
        }
    }
    __syncthreads();
    if (tid == 0) {
        ws_tlo[r] = s_prefix << 20;
        ws_cnt[r] = 0;
    }
}

// ---------------- A1: barrier-free sliced compaction -----------------------
__global__ __launch_bounds__(ATHR) void a1_compact(
    const float* __restrict__ logits,
    const unsigned* __restrict__ ws_tlo,
    int* __restrict__ ws_cnt,
    ull* __restrict__ ws_cand,
    int B, int V)
{
    const int r = blockIdx.x / NS;
    const int s = blockIdx.x % NS;
    const int tid = threadIdx.x;

    const float* row = logits + (long long)r * V;
    const float4* row4 = (const float4*)row;
    const int V4 = V >> 2;
    const int Vt = V4 << 2;
    const float thrF = valOfKey(ws_tlo[r]);
    int* cnt = ws_cnt + r;
    ull* wc = ws_cand + (size_t)r * CAP;

#define SPECG(val, gidx_) do { \
        float _v = (val); \
        if (_v >= thrF) { \
            int _pos = atomicAdd(cnt, 1); \
            if (_pos < CAP) \
                wc[_pos] = ((ull)keyOf(_v) << 32) | (unsigned)(~(unsigned)(gidx_)); \
        } \
    } while (0)

    const int q0 = (int)(((long long)s * V4) / NS);
    const int q1 = (int)(((long long)(s + 1) * V4) / NS);
    int i = q0 + tid;
    for (; i + 3 * ATHR < q1; i += 4 * ATHR) {
        float4 a = row4[i];
        float4 b = row4[i + ATHR];
        float4 c = row4[i + 2 * ATHR];
        float4 d = row4[i + 3 * ATHR];
        SPECG(a.x, i * 4 + 0); SPECG(a.y, i * 4 + 1);
        SPECG(a.z, i * 4 + 2); SPECG(a.w, i * 4 + 3);
        SPECG(b.x, (i + ATHR) * 4 + 0); SPECG(b.y, (i + ATHR) * 4 + 1);
        SPECG(b.z, (i + ATHR) * 4 + 2); SPECG(b.w, (i + ATHR) * 4 + 3);
        SPECG(c.x, (i + 2 * ATHR) * 4 + 0); SPECG(c.y, (i + 2 * ATHR) * 4 + 1);
        SPECG(c.z, (i + 2 * ATHR) * 4 + 2); SPECG(c.w, (i + 2 * ATHR) * 4 + 3);
        SPECG(d.x, (i + 3 * ATHR) * 4 + 0); SPECG(d.y, (i + 3 * ATHR) * 4 + 1);
        SPECG(d.z, (i + 3 * ATHR) * 4 + 2); SPECG(d.w, (i + 3 * ATHR) * 4 + 3);
    }
    for (; i < q1; i += ATHR) {
        float4 a = row4[i];
        SPECG(a.x, i * 4 + 0); SPECG(a.y, i * 4 + 1);
        SPECG(a.z, i * 4 + 2); SPECG(a.w, i * 4 + 3);
    }
    if (s == NS - 1)
        for (int ii = Vt + tid; ii < V; ii += ATHR)
            SPECG(row[ii], ii);
}

// ---------------- B: tail (R3 verbatim) + ws prelude -----------------------
__global__ __launch_bounds__(NTHR) void sampler_tail(
    const float* __restrict__ logits,
    const float* __restrict__ temperature,
    const int* __restrict__ top_kv,
    const float* __restrict__ top_pv,
    const float* __restrict__ gumbel,
    float* __restrict__ out,
    const int* __restrict__ ws_cnt,
    const ull* __restrict__ ws_cand,
    int B, int V, int K, int use_ws)
{
    const int r = blockIdx.x;
    const int tid = threadIdx.x;
    const int lane = tid & 63;
    const int wid = tid >> 6;

    __shared__ ull cand[CAP];                     // 64 KB; aliased as hist
    __shared__ ull cand2[SMALL];                  // 8 KB
    __shared__ unsigned refHist[16 * 257];        // 16.4 KB
    __shared__ int wtotI[16];
    __shared__ float varr[1024];
    __shared__ float Earr[1024];
    __shared__ float sfx[1024];
    __shared__ float sfx2[1024];
    __shared__ unsigned char flagArr[1024];
    __shared__ unsigned bitmap[64];
    __shared__ unsigned s_prefix;
    __shared__ int s_cntgt, s_total, s_lvl;
    __shared__ int s_ncand, s_nc2, s_nkeep, s_rank, s_g0, s_g1;
    __shared__ ull s_amax;
    __shared__ float s_vs;

    unsigned* hist = (unsigned*)cand;

    const float* row = logits + (long long)r * V;
    const float* urow = gumbel + (long long)r * V;

    float traw = temperature[r];
    bool greedy = traw < 1e-5f;
    float t = greedy ? 1.0f : traw;
    int k = top_kv[r];
    if (k < 1) k = 1;
    if (k > V) k = V;
    float p = top_pv[r];

    const float4* row4 = (const float4*)row;
    const int V4 = V >> 2;
    const int Vt = V4 << 2;
    const unsigned cpy = tid & 1u;

#define SPEC1(val, gidx_, thr_) do { \
        float _v = (val); \
        if (_v >= (thr_)) { \
            int _pos = atomicAdd(&s_ncand, 1); \
            if (_pos < CAP) \
                cand[_pos] = ((ull)keyOf(_v) << 32) | (unsigned)(~(unsigned)(gidx_)); \
        } \
    } while (0)

    int ncand = 0;
    bool fastok = false;
    bool haveCand = false;

    // ---------------- prelude: load candidates from workspace ---------------
    if (use_ws) {
        int nc = ws_cnt[r];
        if (nc >= k && nc <= CAP) {
            const ull* wc = ws_cand + (size_t)r * CAP;
            for (int i = tid; i < nc; i += NTHR) cand[i] = wc[i];
            __syncthreads();
            ncand = nc;
            fastok = true;
            haveCand = true;
        }
    }

    if (!haveCand) {
        // ------------- P0: subsample -> speculative threshold ---------------
        for (int i = tid; i < BINS * 2; i += NTHR) hist[i] = 0;
        __syncthreads();
        {
            int f4pos = (int)(((long long)tid * V4) >> 10);
            float4 sv = row4[f4pos];
            H4(sv);
        }
        __syncthreads();
        int ts;
        {
            int tc = 2 * k + 400;
            if (tc > 2400) tc = 2400;
            if (tc < 600) tc = 600;
            ts = (int)(((long long)tc * SS + V - 1) / V);
            if (ts < 4) ts = 4;
        }
        {
            int base = tid << 2;
            int cs = 0;
            #pragma unroll
            for (int j = 0; j < 4; ++j)
                cs += (int)(hist[(base + j) * 2] + hist[(base + j) * 2 + 1]);
            int vv = cs;
            #pragma unroll
            for (int d = 1; d < 64; d <<= 1) {
                int o = __shfl_down(vv, d);
                if (lane + d < 64) vv += o;
            }
            if (lane == 0) wtotI[wid] = vv;
            __syncthreads();
            int off = 0;
            for (int w = wid + 1; w < 16; ++w) off += wtotI[w];
            int mine = vv + off;
            int above = mine - cs;
            if (mine >= ts && above < ts) {
                int run = above;
                for (int b = base + 3; b >= base; --b) {
                    int mb = (int)(hist[b * 2] + hist[b * 2 + 1]);
                    if (run + mb >= ts) { s_prefix = (unsigned)b; break; }
                    run += mb;
                }
            }
            if (tid == 0) s_ncand = 0;
            __syncthreads();
        }
        unsigned tlo = s_prefix << 20;
        float thrF = valOfKey(tlo);

        // ------------- P1: single-pass speculative compaction ---------------
        {
            int i = tid;
            for (; i + 3 * NTHR < V4; i += 4 * NTHR) {
                float4 a = row4[i];
                float4 b = row4[i + NTHR];
                float4 c = row4[i + 2 * NTHR];
                float4 d = row4[i + 3 * NTHR];
                SPEC1(a.x, i * 4 + 0, thrF); SPEC1(a.y, i * 4 + 1, thrF);
                SPEC1(a.z, i * 4 + 2, thrF); SPEC1(a.w, i * 4 + 3, thrF);
                SPEC1(b.x, (i + NTHR) * 4 + 0, thrF); SPEC1(b.y, (i + NTHR) * 4 + 1, thrF);
                SPEC1(b.z, (i + NTHR) * 4 + 2, thrF); SPEC1(b.w, (i + NTHR) * 4 + 3, thrF);
                SPEC1(c.x, (i + 2 * NTHR) * 4 + 0, thrF); SPEC1(c.y, (i + 2 * NTHR) * 4 + 1, thrF);
                SPEC1(c.z, (i + 2 * NTHR) * 4 + 2, thrF); SPEC1(c.w, (i + 2 * NTHR) * 4 + 3, thrF);
                SPEC1(d.x, (i + 3 * NTHR) * 4 + 0, thrF); SPEC1(d.y, (i + 3 * NTHR) * 4 + 1, thrF);
                SPEC1(d.z, (i + 3 * NTHR) * 4 + 2, thrF); SPEC1(d.w, (i + 3 * NTHR) * 4 + 3, thrF);
            }
            for (; i < V4; i += NTHR) {
                float4 a = row4[i];
                SPEC1(a.x, i * 4 + 0, thrF); SPEC1(a.y, i * 4 + 1, thrF);
                SPEC1(a.z, i * 4 + 2, thrF); SPEC1(a.w, i * 4 + 3, thrF);
            }
            for (int ii = Vt + tid; ii < V; ii += NTHR)
                SPEC1(row[ii], ii, thrF);
        }
        __syncthreads();
        ncand = s_ncand;
        fastok = (ncand >= k && ncand <= CAP);

        // ------------- exact two-pass fallback ------------------------------
        if (!fastok) {
            for (int i = tid; i < BINS * 2; i += NTHR) hist[i] = 0;
            __syncthreads();
            {
                int i = tid;
                for (; i + 3 * NTHR < V4; i += 4 * NTHR) {
                    float4 a = row4[i];
                    float4 b = row4[i + NTHR];
                    float4 c = row4[i + 2 * NTHR];
                    float4 d = row4[i + 3 * NTHR];
                    H4(a); H4(b); H4(c); H4(d);
                }
                for (; i < V4; i += NTHR) { float4 a = row4[i]; H4(a); }
                for (int ii = Vt + tid; ii < V; ii += NTHR)
                    atomicAdd(&hist[((keyOf(row[ii]) >> 20) << 1) | cpy], 1u);
            }
            __syncthreads();
            {
                int base = tid << 2;
                int cs = 0;
                #pragma unroll
                for (int j = 0; j < 4; ++j)
                    cs += (int)(hist[(base + j) * 2] + hist[(base + j) * 2 + 1]);
                int vv = cs;
                #pragma unroll
                for (int d = 1; d < 64; d <<= 1) {
                    int o = __shfl_down(vv, d);
                    if (lane + d < 64) vv += o;
                }
                if (lane == 0) wtotI[wid] = vv;
                __syncthreads();
                int off = 0;
                for (int w = wid + 1; w < 16; ++w) off += wtotI[w];
                int mine = vv + off;
                int above = mine - cs;
                if (mine >= k && above < k) {
                    int run = above;
                    for (int b = base + 3; b >= base; --b) {
                        int mb = (int)(hist[b * 2] + hist[b * 2 + 1]);
                        if (run + mb >= k) {
                            s_prefix = (unsigned)b; s_cntgt = run; s_total = run + mb; s_lvl = 0;
                            break;
                        }
                        run += mb;
                    }
                }
            }
            for (int level = 1; level <= 2; ++level) {
                __syncthreads();
                if (s_total <= CAP) break;
                for (int i = tid; i < 512; i += NTHR) hist[i] = 0;
                __syncthreads();
                unsigned pfx = s_prefix;
                const int msh = 32 - (12 + 8 * (level - 1));
                const int bsh = msh - 8;
                for (int i = tid; i < V4; i += NTHR) {
                    float4 l4 = row4[i];
                    float vv4[4] = { l4.x, l4.y, l4.z, l4.w };
                    #pragma unroll
                    for (int j = 0; j < 4; ++j) {
                        unsigned key = keyOf(vv4[j]);
                        if ((key >> msh) == pfx)
                            atomicAdd(&hist[(((key >> bsh) & 255u) << 1) | cpy], 1u);
                    }
                }
                for (int i = Vt + tid; i < V; i += NTHR) {
                    unsigned key = keyOf(row[i]);
                    if ((key >> msh) == pfx)
                        atomicAdd(&hist[(((key >> bsh) & 255u) << 1) | cpy], 1u);
                }
                __syncthreads();
                if (tid == 0) {
                    int run = s_cntgt;
                    for (int b = 255; b >= 0; --b) {
                        int mb = (int)(hist[b * 2] + hist[b * 2 + 1]);
                        if (run + mb >= k) {
                            s_prefix = (pfx << 8) | (unsigned)b; s_cntgt = run; s_total = run + mb;
                            break;
                        }
                        run += mb;
                    }
                    s_lvl = level;
                }
            }
            __syncthreads();
            unsigned tlo2 = s_prefix << (20 - 8 * s_lvl);
            float thrF2 = valOfKey(tlo2);
            if (tid == 0) s_ncand = 0;
            __syncthreads();
            {
                int i = tid;
                for (; i + 3 * NTHR < V4; i += 4 * NTHR) {
                    float4 a = row4[i];
                    float4 b = row4[i + NTHR];
                    float4 c = row4[i + 2 * NTHR];
                    float4 d = row4[i + 3 * NTHR];
                    SPEC1(a.x, i * 4 + 0, thrF2); SPEC1(a.y, i * 4 + 1, thrF2);
                    SPEC1(a.z, i * 4 + 2, thrF2); SPEC1(a.w, i * 4 + 3, thrF2);
                    SPEC1(b.x, (i + NTHR) * 4 + 0, thrF2); SPEC1(b.y, (i + NTHR) * 4 + 1, thrF2);
                    SPEC1(b.z, (i + NTHR) * 4 + 2, thrF2); SPEC1(b.w, (i + NTHR) * 4 + 3, thrF2);
                    SPEC1(c.x, (i + 2 * NTHR) * 4 + 0, thrF2); SPEC1(c.y, (i + 2 * NTHR) * 4 + 1, thrF2);
                    SPEC1(c.z, (i + 2 * NTHR) * 4 + 2, thrF2); SPEC1(c.w, (i + 2 * NTHR) * 4 + 3, thrF2);
                    SPEC1(d.x, (i + 3 * NTHR) * 4 + 0, thrF2); SPEC1(d.y, (i + 3 * NTHR) * 4 + 1, thrF2);
                    SPEC1(d.z, (i + 3 * NTHR) * 4 + 2, thrF2); SPEC1(d.w, (i + 3 * NTHR) * 4 + 3, thrF2);
                }
                for (; i < V4; i += NTHR) {
                    float4 a = row4[i];
                    SPEC1(a.x, i * 4 + 0, thrF2); SPEC1(a.y, i * 4 + 1, thrF2);
                    SPEC1(a.z, i * 4 + 2, thrF2); SPEC1(a.w, i * 4 + 3, thrF2);
                }
                for (int ii = Vt + tid; ii < V; ii += NTHR)
                    SPEC1(row[ii], ii, thrF2);
            }
            __syncthreads();
            ncand = s_ncand;
            if (ncand > CAP) ncand = CAP;
            if (k > ncand) k = ncand;
        }
    }
    if (k > ncand) k = ncand;                             // safety

    // ------- Phase 2.5: adaptive exact/near-exact refine (ncand > 1024) ------
    bool fromC2 = false;
    bool bigSort = false;
    if (ncand > SMALL) {
        unsigned pfx; int run; int bb;
        if (fastok) { pfx = 0u; run = 0; bb = 32; }
        else { pfx = s_prefix; run = s_cntgt; bb = 20 - 8 * s_lvl; }
        int totR = ncand;
        while (totR > SMALL - 16 && bb > 0) {
            int step = (bb >= 8) ? 8 : bb;
            bb -= step;
            int nbins = 1 << step;
            for (int i = tid; i < 16 * 257; i += NTHR) refHist[i] = 0;
            __syncthreads();
            {
                const int sh = bb + step;
                const unsigned lc = (unsigned)(lane & 15) * 257u;
                for (int i = tid; i < ncand; i += NTHR) {
                    unsigned key = (unsigned)(cand[i] >> 32);
                    bool in = (sh >= 32) || ((key >> sh) == pfx);
                    if (in)
                        atomicAdd(&refHist[lc + ((key >> bb) & (unsigned)(nbins - 1))], 1u);
                }
            }
            __syncthreads();
            int cnt = 0;
            if (tid < 256 && tid < nbins) {
                #pragma unroll
                for (int c = 0; c < 16; ++c) cnt += (int)refHist[c * 257 + tid];
            }
            int vv = cnt;
            #pragma unroll
            for (int d = 1; d < 64; d <<= 1) {
                int o = __shfl_down(vv, d);
                if (lane + d < 64) vv += o;
            }
            if (tid < 256 && lane == 0) wtotI[wid] = vv;
            __syncthreads();
            if (tid < 256) {
                int off = 0;
                for (int w = wid + 1; w < 4; ++w) off += wtotI[w];
                int incl = vv + off;
                int abv = incl - cnt;
                int kk = k - run;
                if (incl >= kk && abv < kk) {
                    s_prefix = (pfx << step) | (unsigned)tid;
                    s_cntgt = run + abv;
                    s_total = run + abv + cnt;
                }
            }
            __syncthreads();
            pfx = s_prefix;
            run = s_cntgt;
            totR = s_total;
        }
        unsigned tref0 = (bb > 0) ? (pfx << bb) : pfx;
        unsigned tref = (tref0 >= GUARD) ? (tref0 - GUARD) : 0u;
        if (tid == 0) s_nc2 = 0;
        __syncthreads();
        for (int i = tid; i < ncand; i += NTHR) {
            ull cv = cand[i];
            bool pred = ((unsigned)(cv >> 32) >= tref);
            ull mask = __ballot(pred ? 1 : 0);
            if (mask) {
                int leader = __ffsll(mask) - 1;
                int cnt2 = __popcll(mask);
                int bpos = 0;
                if (lane == leader) bpos = atomicAdd(&s_nc2, cnt2);
                bpos = __shfl(bpos, leader);
                if (pred) {
                    int pos = bpos + __popcll(mask & ((1ULL << lane) - 1ULL));
                    if (pos < SMALL) cand2[pos] = cv;
                }
            }
        }
        __syncthreads();
        int nc2 = s_nc2;
        if (nc2 <= SMALL) { ncand = nc2; fromC2 = true; }
        else bigSort = true;
    }

    // ---------------- Phase 3: descending sort -------------------------------
    if (!bigSort) {
        const ull* src = fromC2 ? cand2 : cand;
        ull v = (tid < ncand) ? src[tid] : 0ULL;
        int seg = 0;
        #pragma unroll
        for (int size = 2; size <= SMALL; size <<= 1) {
            #pragma unroll
            for (int stride = size >> 1; stride > 0; stride >>= 1) {
                ull o;
                if (stride < 64) {
                    o = shflXor64(v, stride);
                } else {
                    cand[seg * SMALL + tid] = v;
                    __syncthreads();
                    o = cand[seg * SMALL + (tid ^ stride)];
                    seg ^= 1;
                }
                bool takeMax = (((tid & size) == 0) == ((tid & stride) == 0));
                ull mx = (v > o) ? v : o;
                ull mn = (v > o) ? o : v;
                v = takeMax ? mx : mn;
            }
        }
        cand[tid] = v;
        varr[tid] = (tid < ncand) ? (valOfKey((unsigned)(v >> 32)) / t) : NEG_BIG;
        __syncthreads();
    } else {
        int P = 2; while (P < ncand) P <<= 1;
        for (int i = ncand + tid; i < P; i += NTHR) cand[i] = 0ULL;
        __syncthreads();
        for (int size = 2; size <= P; size <<= 1) {
            for (int stride = size >> 1; stride > 0; stride >>= 1) {
                for (int i = tid; i < P; i += NTHR) {
                    int j = i ^ stride;
                    if (j > i) {
                        ull a = cand[i], b = cand[j];
                        bool up = ((i & size) == 0);
                        bool sw = up ? (a < b) : (a > b);
                        if (sw) { cand[i] = b; cand[j] = a; }
                    }
                }
                __syncthreads();
            }
        }
        for (int i = tid; i < 1024; i += NTHR)
            varr[i] = (i < ncand) ? (valOfKey((unsigned)(cand[i] >> 32)) / t) : NEG_BIG;
        __syncthreads();
    }

    // ---------------- Phase 4: top-k/top-p/sample ----------------------------
    const float m = varr[0];
    const float tkeyV = varr[k - 1];
    int ntop = k;
    while (ntop < ncand) {
        float vi = (ntop < 1024) ? varr[ntop]
                                 : (valOfKey((unsigned)(cand[ntop] >> 32)) / t);
        if (vi != tkeyV) break;
        ++ntop;
    }
    if (ntop > 1024) ntop = 1024;

    {
        float e = (tid < ntop) ? expf(varr[tid] - m) : 0.0f;
        Earr[tid] = e;
        sfx[tid] = e;
        if (tid == 0) { s_nkeep = 0; s_rank = 0; s_amax = 0ULL; }
        if (tid < 64) bitmap[tid] = 0;
    }
    __syncthreads();
    {
        float* A = sfx;
        float* Bf = sfx2;
        #pragma unroll
        for (int d = 1; d < 1024; d <<= 1) {
            float t0 = (tid + d < 1024) ? A[tid + d] : 0.0f;
            Bf[tid] = A[tid] + t0;
            __syncthreads();
            float* tmp = A; A = Bf; Bf = tmp;
        }
    }
    const float Zp = sfx[0];
    const float cmp = 1.0f - p;
    {
        int local = 0;
        for (int i = tid; i < ntop; i += NTHR)
            if (sfx[i] / Zp > cmp) local++;
        #pragma unroll
        for (int d = 1; d < 64; d <<= 1) local += __shfl_xor(local, d);
        if (lane == 0 && local) atomicAdd(&s_nkeep, local);
    }
    __syncthreads();
    const int nkeep = s_nkeep;
    if (tid == 0) {
        float vb = varr[nkeep - 1];
        int g0 = nkeep - 1;
        while (g0 > 0 && varr[g0 - 1] == vb) --g0;
        int g1 = nkeep;
        while (g1 < ntop && varr[g1] == vb) ++g1;
        s_g0 = g0; s_g1 = g1;
    }
    __syncthreads();
    const int g0 = s_g0, g1 = s_g1;
    const int mkeep = nkeep - g0;
    for (int i = g0 + tid; i < g1; i += NTHR) {
        unsigned gi = ~(unsigned)(cand[i] & 0xFFFFFFFFull);
        int rk = 0;
        for (int j = g0; j < g1; ++j) {
            unsigned gj = ~(unsigned)(cand[j] & 0xFFFFFFFFull);
            if (gj > gi) rk++;
        }
        flagArr[i] = (rk < mkeep) ? 1 : 0;
    }
    __syncthreads();

    const float Z2 = (nkeep < 1024) ? (Zp - sfx[nkeep]) : Zp;
    const float L = logf(Z2);

    {
        ull lm = 0ULL;
        for (int i = tid; i < g1; i += NTHR) {
            if (i < g0 || flagArr[i]) {
                unsigned lo = (unsigned)(cand[i] & 0xFFFFFFFFull);
                unsigned gidx = ~lo;
                float u = urow[gidx];
                float q = -((u >= RMAX_F) ? RMAX_LOG_F : logf(u));
                float prob = Earr[i] / Z2;
                float ratio = greedy ? prob : (prob / q);
                ull comp = ((ull)__float_as_uint(ratio) << 32) | lo;
                if (comp > lm) lm = comp;
                if (gidx < 2048) atomicOr(&bitmap[gidx >> 5], 1u << (gidx & 31));
            }
        }
        #pragma unroll
        for (int d = 1; d < 64; d <<= 1) {
            ull o = shflXor64(lm, d);
            if (o > lm) lm = o;
        }
        if (lane == 0 && lm) atomicMax(&s_amax, lm);
    }
    __syncthreads();
    const unsigned samp_lo = (unsigned)(s_amax & 0xFFFFFFFFull);
    const unsigned samp = ~samp_lo;
    for (int i = tid; i < ntop; i += NTHR)
        if ((unsigned)(cand[i] & 0xFFFFFFFFull) == samp_lo) s_vs = varr[i];
    __syncthreads();
    const float lp_s = (s_vs - m) - L;
    {
        int local = 0;
        for (int i = tid; i < nkeep; i += NTHR)
            if ((varr[i] - m) - L > lp_s) local++;
        #pragma unroll
        for (int d = 1; d < 64; d <<= 1) local += __shfl_xor(local, d);
        if (lane == 0 && local) atomicAdd(&s_rank, local);
    }
    __syncthreads();

    // ---------------- Phase 5: outputs ---------------------------------------
    float* o_samp = out;
    float* o_idx  = out + B;
    float* o_lp   = out + B + (long long)B * (K + 1);
    float* o_rank = out + B + 2LL * B * (K + 1);
    const long long rowo = (long long)r * (K + 1);
    const int ntk = (nkeep < K) ? nkeep : K;

    if (tid < g1) {
        const int i = tid;
        bool kept = (i < g0) || flagArr[i];
        if (kept) {
            float v = varr[i];
            int rs, re, base;
            if (i >= g0) { rs = g0; re = g1; base = g0; }
            else {
                rs = i; while (rs > 0 && varr[rs - 1] == v) --rs;
                re = i + 1; while (re < g1 && varr[re] == v) ++re;
                base = rs;
            }
            if (base < ntk) {
                unsigned myidx = ~(unsigned)(cand[i] & 0xFFFFFFFFull);
                int cnt = 0;
                for (int j = rs; j < re; ++j) {
                    if (j == i) continue;
                    if (j >= g0 && !flagArr[j]) continue;
                    unsigned gj = ~(unsigned)(cand[j] & 0xFFFFFFFFull);
                    if (gj < myidx) cnt++;
                }
                int slot = base + cnt;
                if (slot < ntk) {
                    o_idx[rowo + 1 + slot] = (float)myidx;
                    o_lp[rowo + 1 + slot] = (v - m) - L;
                }
            }
        }
    }

    if (tid == 0) {
        o_samp[r] = (float)samp;
        o_idx[rowo] = (float)samp;
        o_lp[rowo] = lp_s;
        o_rank[r] = (float)s_rank;
        if (nkeep < K) {
            int j = 0;
            for (int c = nkeep; c < K; ++c) {
                while (bitmap[j >> 5] & (1u << (j & 31))) ++j;
                o_idx[rowo + 1 + c] = (float)j;
                o_lp[rowo + 1 + c] = NEG_BIG;
                ++j;
            }
        }
    }
}

extern "C" void kernel_launch(void* const* d_in, const int* in_sizes, int n_in,
                              void* d_out, int out_size, void* d_ws, size_t ws_size,
                              hipStream_t stream) {
    const float* logits      = (const float*)d_in[0];
    const float* temperature = (const float*)d_in[1];
    const int*   top_k       = (const int*)d_in[2];
    const float* top_p       = (const float*)d_in[3];
    const float* gumbel      = (const float*)d_in[4];
    int B = in_sizes[1];
    int V = in_sizes[0] / B;
    int K = (out_size / B - 4) / 2;

    // workspace layout: [B x int cnt][B x unsigned tlo][pad to 256][B x CAP ull]
    size_t off = ((size_t)B * 8 + 255) & ~(size_t)255;
    size_t need = off + (size_t)B * CAP * sizeof(ull);

    if (d_ws != nullptr && ws_size >= need) {
        int* ws_cnt = (int*)d_ws;
        unsigned* ws_tlo = (unsigned*)((char*)d_ws + (size_t)B * 4);
        ull* ws_cand = (ull*)((char*)d_ws + off);
        a0_thresh<<<B, NTHR, 0, stream>>>(logits, top_k, ws_cnt, ws_tlo, B, V);
        a1_compact<<<B * NS, ATHR, 0, stream>>>(logits, ws_tlo, ws_cnt, ws_cand, B, V);
        sampler_tail<<<B, NTHR, 0, stream>>>(logits, temperature, top_k, top_p,
                                             gumbel, (float*)d_out, ws_cnt, ws_cand,
                                             B, V, K, 1);
    } else {
        sampler_tail<<<B, NTHR, 0, stream>>>(logits, temperature, top_k, top_p,
                                             gumbel, (float*)d_out, nullptr, nullptr,
                                             B, V, K, 0);
    }
}

// Round 5
// 279.195 us; speedup vs baseline: 2.2308x; 2.2308x over previous
//
#include <hip/hip_runtime.h>
#include <math.h>

#define NTHR 1024
#define CAP 8192
#define BINS 4096
#define SMALL 1024
#define GUARD 16u
#define SS 4096
#define NS 8
#define ATHR 256
#define SEGCAP 1024          /* CAP / NS */

#define RMAX_F 0.9999999403953552f
#define RMAX_LOG_F -5.960464477539063e-08f
#define NEG_BIG -3.0e38f

typedef unsigned long long ull;

__device__ __forceinline__ unsigned keyOf(float v) {
    unsigned b = __float_as_uint(v);
    return (b & 0x80000000u) ? ~b : (b | 0x80000000u);
}
__device__ __forceinline__ float valOfKey(unsigned k) {
    unsigned b = (k & 0x80000000u) ? (k ^ 0x80000000u) : ~k;
    return __uint_as_float(b);
}
__device__ __forceinline__ ull shflXor64(ull v, int m) {
    int lo = __shfl_xor((int)(unsigned)v, m);
    int hi = __shfl_xor((int)(unsigned)(v >> 32), m);
    return ((ull)(unsigned)hi << 32) | (unsigned)lo;
}

// ---------------------------------------------------------------------------
// R5: split pipeline, a1 repaired.
//  R4 lesson: cross-block GLOBAL atomic append = serialization cliff (390 us).
//  a1 now stages survivors in a block-private LDS buffer with an LDS counter
//  (wave-aggregated), then flushes contiguously to a private ws segment and
//  stores the count once. 8 slices/row -> 8 blocks/CU, 32 waves/CU, no
//  cross-block traffic. Quad-max mask + ffs drain keeps the common path at
//  ~1.5 VALU inst/element.
//  Tail: gathers the 8 segments; any overflow / count outside [k,CAP] ->
//  verbatim exact in-kernel fallback (correctness never depends on ws).
// ---------------------------------------------------------------------------

#define H4(v4) do { \
        atomicAdd(&hist[((keyOf((v4).x) >> 20) << 1) | cpy], 1u); \
        atomicAdd(&hist[((keyOf((v4).y) >> 20) << 1) | cpy], 1u); \
        atomicAdd(&hist[((keyOf((v4).z) >> 20) << 1) | cpy], 1u); \
        atomicAdd(&hist[((keyOf((v4).w) >> 20) << 1) | cpy], 1u); \
    } while (0)

// ---------------- A0: per-row speculative threshold ------------------------
__global__ __launch_bounds__(NTHR) void a0_thresh(
    const float* __restrict__ logits,
    const int* __restrict__ top_kv,
    unsigned* __restrict__ ws_tlo,
    int B, int V)
{
    const int r = blockIdx.x;
    const int tid = threadIdx.x;
    const int lane = tid & 63;
    const int wid = tid >> 6;
    __shared__ unsigned hist[BINS * 2];
    __shared__ int wtotI[16];
    __shared__ unsigned s_prefix;

    const float* row = logits + (long long)r * V;
    const float4* row4 = (const float4*)row;
    const int V4 = V >> 2;
    const unsigned cpy = tid & 1u;

    int k = top_kv[r];
    if (k < 1) k = 1;
    if (k > V) k = V;

    for (int i = tid; i < BINS * 2; i += NTHR) hist[i] = 0;
    __syncthreads();
    {
        int f4pos = (int)(((long long)tid * V4) >> 10);   // 4096 spread samples
        float4 sv = row4[f4pos];
        H4(sv);
    }
    __syncthreads();
    int ts;
    {
        int tc = 2 * k + 400;
        if (tc > 2400) tc = 2400;
        if (tc < 600) tc = 600;
        ts = (int)(((long long)tc * SS + V - 1) / V);
        if (ts < 4) ts = 4;
    }
    {
        int base = tid << 2;
        int cs = 0;
        #pragma unroll
        for (int j = 0; j < 4; ++j)
            cs += (int)(hist[(base + j) * 2] + hist[(base + j) * 2 + 1]);
        int vv = cs;
        #pragma unroll
        for (int d = 1; d < 64; d <<= 1) {
            int o = __shfl_down(vv, d);
            if (lane + d < 64) vv += o;
        }
        if (lane == 0) wtotI[wid] = vv;
        __syncthreads();
        int off = 0;
        for (int w = wid + 1; w < 16; ++w) off += wtotI[w];
        int mine = vv + off;
        int above = mine - cs;
        if (mine >= ts && above < ts) {                   // exactly one thread
            int run = above;
            for (int b = base + 3; b >= base; --b) {
                int mb = (int)(hist[b * 2] + hist[b * 2 + 1]);
                if (run + mb >= ts) { s_prefix = (unsigned)b; break; }
                run += mb;
            }
        }
    }
    __syncthreads();
    if (tid == 0) ws_tlo[r] = s_prefix << 20;
}

// ---------------- A1: LDS-staged sliced compaction -------------------------
__global__ __launch_bounds__(ATHR) void a1_compact(
    const float* __restrict__ logits,
    const unsigned* __restrict__ ws_tlo,
    int* __restrict__ ws_cnt,
    ull* __restrict__ ws_cand,
    int B, int V)
{
    const int r = blockIdx.x / NS;
    const int s = blockIdx.x % NS;
    const int tid = threadIdx.x;
    __shared__ ull seg[SEGCAP];
    __shared__ int scnt;
    if (tid == 0) scnt = 0;
    __syncthreads();

    const float* row = logits + (long long)r * V;
    const float4* row4 = (const float4*)row;
    const int V4 = V >> 2;
    const int Vt = V4 << 2;
    const float thrF = valOfKey(ws_tlo[r]);

#define APPL(val, gidx_, pred_) do { \
        if (pred_) { \
            int _pos = atomicAdd(&scnt, 1); \
            if (_pos < SEGCAP) \
                seg[_pos] = ((ull)keyOf(val) << 32) | (unsigned)(~(unsigned)(gidx_)); \
        } \
    } while (0)

    const int q0 = (int)(((long long)s * V4) / NS);
    const int q1 = (int)(((long long)(s + 1) * V4) / NS);
    int i = q0 + tid;
    for (; i + 3 * ATHR < q1; i += 4 * ATHR) {
        float4 a = row4[i];
        float4 b = row4[i + ATHR];
        float4 c = row4[i + 2 * ATHR];
        float4 d = row4[i + 3 * ATHR];
        float m0 = fmaxf(fmaxf(a.x, a.y), fmaxf(a.z, a.w));
        float m1 = fmaxf(fmaxf(b.x, b.y), fmaxf(b.z, b.w));
        float m2 = fmaxf(fmaxf(c.x, c.y), fmaxf(c.z, c.w));
        float m3 = fmaxf(fmaxf(d.x, d.y), fmaxf(d.z, d.w));
        unsigned qm = (m0 >= thrF ? 1u : 0u) | (m1 >= thrF ? 2u : 0u)
                    | (m2 >= thrF ? 4u : 0u) | (m3 >= thrF ? 8u : 0u);
        while (__any((int)qm)) {                          // rare drain loop
            bool have = qm != 0u;
            int q = __ffs((int)qm) - 1;
            if (q < 0) q = 0;
            float4 vq = (q == 0) ? a : (q == 1) ? b : (q == 2) ? c : d;
            int base4 = (i + q * ATHR) * 4;
            APPL(vq.x, base4 + 0, have && vq.x >= thrF);
            APPL(vq.y, base4 + 1, have && vq.y >= thrF);
            APPL(vq.z, base4 + 2, have && vq.z >= thrF);
            APPL(vq.w, base4 + 3, have && vq.w >= thrF);
            qm &= qm - 1u;
        }
    }
    for (; i < q1; i += ATHR) {
        float4 a = row4[i];
        APPL(a.x, i * 4 + 0, a.x >= thrF);
        APPL(a.y, i * 4 + 1, a.y >= thrF);
        APPL(a.z, i * 4 + 2, a.z >= thrF);
        APPL(a.w, i * 4 + 3, a.w >= thrF);
    }
    if (s == NS - 1)
        for (int ii = Vt + tid; ii < V; ii += ATHR) {
            float lv = row[ii];
            APPL(lv, ii, lv >= thrF);
        }
    __syncthreads();
    int cnt = scnt;
    if (tid == 0) ws_cnt[r * NS + s] = cnt;               // raw (overflow detect)
    int wn = cnt < SEGCAP ? cnt : SEGCAP;
    ull* wc = ws_cand + (size_t)r * CAP + (size_t)s * SEGCAP;
    for (int j = tid; j < wn; j += ATHR) wc[j] = seg[j];  // coalesced flush
}

// ---------------- B: tail + segment-gather prelude -------------------------
__global__ __launch_bounds__(NTHR) void sampler_tail(
    const float* __restrict__ logits,
    const float* __restrict__ temperature,
    const int* __restrict__ top_kv,
    const float* __restrict__ top_pv,
    const float* __restrict__ gumbel,
    float* __restrict__ out,
    const int* __restrict__ ws_cnt,
    const ull* __restrict__ ws_cand,
    int B, int V, int K, int use_ws)
{
    const int r = blockIdx.x;
    const int tid = threadIdx.x;
    const int lane = tid & 63;
    const int wid = tid >> 6;

    __shared__ ull cand[CAP];                     // 64 KB; aliased as hist
    __shared__ ull cand2[SMALL];                  // 8 KB
    __shared__ unsigned refHist[16 * 257];        // 16.4 KB
    __shared__ int wtotI[16];
    __shared__ int segoff[NS + 1];
    __shared__ float varr[1024];
    __shared__ float Earr[1024];
    __shared__ float sfx[1024];
    __shared__ float sfx2[1024];
    __shared__ unsigned char flagArr[1024];
    __shared__ unsigned bitmap[64];
    __shared__ unsigned s_prefix;
    __shared__ int s_cntgt, s_total, s_lvl;
    __shared__ int s_ncand, s_nc2, s_nkeep, s_rank, s_g0, s_g1;
    __shared__ ull s_amax;
    __shared__ float s_vs;

    unsigned* hist = (unsigned*)cand;

    const float* row = logits + (long long)r * V;
    const float* urow = gumbel + (long long)r * V;

    float traw = temperature[r];
    bool greedy = traw < 1e-5f;
    float t = greedy ? 1.0f : traw;
    int k = top_kv[r];
    if (k < 1) k = 1;
    if (k > V) k = V;
    float p = top_pv[r];

    const float4* row4 = (const float4*)row;
    const int V4 = V >> 2;
    const int Vt = V4 << 2;
    const unsigned cpy = tid & 1u;

#define SPEC1(val, gidx_, thr_) do { \
        float _v = (val); \
        if (_v >= (thr_)) { \
            int _pos = atomicAdd(&s_ncand, 1); \
            if (_pos < CAP) \
                cand[_pos] = ((ull)keyOf(_v) << 32) | (unsigned)(~(unsigned)(gidx_)); \
        } \
    } while (0)

    int ncand = 0;
    bool fastok = false;
    bool haveCand = false;

    // ---------------- prelude: gather ws segments ---------------------------
    if (use_ws) {
        if (tid == 0) {
            int acc = 0;
            bool ok = true;
            for (int s2 = 0; s2 < NS; ++s2) {
                int c = ws_cnt[r * NS + s2];
                segoff[s2] = acc;
                if (c < 0 || c > SEGCAP) ok = false;
                else acc += c;
            }
            segoff[NS] = acc;
            s_ncand = ok ? acc : -1;
        }
        __syncthreads();
        int nc = s_ncand;
        if (nc >= k && nc <= CAP) {
            const ull* wc = ws_cand + (size_t)r * CAP;
            for (int s2 = 0; s2 < NS; ++s2) {
                int c0 = segoff[s2], c1 = segoff[s2 + 1];
                for (int i = c0 + tid; i < c1; i += NTHR)
                    cand[i] = wc[(size_t)s2 * SEGCAP + (i - c0)];
            }
            __syncthreads();
            ncand = nc;
            fastok = true;
            haveCand = true;
        }
    }

    if (!haveCand) {
        // ------------- P0: subsample -> speculative threshold ---------------
        for (int i = tid; i < BINS * 2; i += NTHR) hist[i] = 0;
        __syncthreads();
        {
            int f4pos = (int)(((long long)tid * V4) >> 10);
            float4 sv = row4[f4pos];
            H4(sv);
        }
        __syncthreads();
        int ts;
        {
            int tc = 2 * k + 400;
            if (tc > 2400) tc = 2400;
            if (tc < 600) tc = 600;
            ts = (int)(((long long)tc * SS + V - 1) / V);
            if (ts < 4) ts = 4;
        }
        {
            int base = tid << 2;
            int cs = 0;
            #pragma unroll
            for (int j = 0; j < 4; ++j)
                cs += (int)(hist[(base + j) * 2] + hist[(base + j) * 2 + 1]);
            int vv = cs;
            #pragma unroll
            for (int d = 1; d < 64; d <<= 1) {
                int o = __shfl_down(vv, d);
                if (lane + d < 64) vv += o;
            }
            if (lane == 0) wtotI[wid] = vv;
            __syncthreads();
            int off = 0;
            for (int w = wid + 1; w < 16; ++w) off += wtotI[w];
            int mine = vv + off;
            int above = mine - cs;
            if (mine >= ts && above < ts) {
                int run = above;
                for (int b = base + 3; b >= base; --b) {
                    int mb = (int)(hist[b * 2] + hist[b * 2 + 1]);
                    if (run + mb >= ts) { s_prefix = (unsigned)b; break; }
                    run += mb;
                }
            }
            if (tid == 0) s_ncand = 0;
            __syncthreads();
        }
        unsigned tlo = s_prefix << 20;
        float thrF = valOfKey(tlo);

        // ------------- P1: single-pass speculative compaction ---------------
        {
            int i = tid;
            for (; i + 3 * NTHR < V4; i += 4 * NTHR) {
                float4 a = row4[i];
                float4 b = row4[i + NTHR];
                float4 c = row4[i + 2 * NTHR];
                float4 d = row4[i + 3 * NTHR];
                SPEC1(a.x, i * 4 + 0, thrF); SPEC1(a.y, i * 4 + 1, thrF);
                SPEC1(a.z, i * 4 + 2, thrF); SPEC1(a.w, i * 4 + 3, thrF);
                SPEC1(b.x, (i + NTHR) * 4 + 0, thrF); SPEC1(b.y, (i + NTHR) * 4 + 1, thrF);
                SPEC1(b.z, (i + NTHR) * 4 + 2, thrF); SPEC1(b.w, (i + NTHR) * 4 + 3, thrF);
                SPEC1(c.x, (i + 2 * NTHR) * 4 + 0, thrF); SPEC1(c.y, (i + 2 * NTHR) * 4 + 1, thrF);
                SPEC1(c.z, (i + 2 * NTHR) * 4 + 2, thrF); SPEC1(c.w, (i + 2 * NTHR) * 4 + 3, thrF);
                SPEC1(d.x, (i + 3 * NTHR) * 4 + 0, thrF); SPEC1(d.y, (i + 3 * NTHR) * 4 + 1, thrF);
                SPEC1(d.z, (i + 3 * NTHR) * 4 + 2, thrF); SPEC1(d.w, (i + 3 * NTHR) * 4 + 3, thrF);
            }
            for (; i < V4; i += NTHR) {
                float4 a = row4[i];
                SPEC1(a.x, i * 4 + 0, thrF); SPEC1(a.y, i * 4 + 1, thrF);
                SPEC1(a.z, i * 4 + 2, thrF); SPEC1(a.w, i * 4 + 3, thrF);
            }
            for (int ii = Vt + tid; ii < V; ii += NTHR)
                SPEC1(row[ii], ii, thrF);
        }
        __syncthreads();
        ncand = s_ncand;
        fastok = (ncand >= k && ncand <= CAP);

        // ------------- exact two-pass fallback ------------------------------
        if (!fastok) {
            for (int i = tid; i < BINS * 2; i += NTHR) hist[i] = 0;
            __syncthreads();
            {
                int i = tid;
                for (; i + 3 * NTHR < V4; i += 4 * NTHR) {
                    float4 a = row4[i];
                    float4 b = row4[i + NTHR];
                    float4 c = row4[i + 2 * NTHR];
                    float4 d = row4[i + 3 * NTHR];
                    H4(a); H4(b); H4(c); H4(d);
                }
                for (; i < V4; i += NTHR) { float4 a = row4[i]; H4(a); }
                for (int ii = Vt + tid; ii < V; ii += NTHR)
                    atomicAdd(&hist[((keyOf(row[ii]) >> 20) << 1) | cpy], 1u);
            }
            __syncthreads();
            {
                int base = tid << 2;
                int cs = 0;
                #pragma unroll
                for (int j = 0; j < 4; ++j)
                    cs += (int)(hist[(base + j) * 2] + hist[(base + j) * 2 + 1]);
                int vv = cs;
                #pragma unroll
                for (int d = 1; d < 64; d <<= 1) {
                    int o = __shfl_down(vv, d);
                    if (lane + d < 64) vv += o;
                }
                if (lane == 0) wtotI[wid] = vv;
                __syncthreads();
                int off = 0;
                for (int w = wid + 1; w < 16; ++w) off += wtotI[w];
                int mine = vv + off;
                int above = mine - cs;
                if (mine >= k && above < k) {
                    int run = above;
                    for (int b = base + 3; b >= base; --b) {
                        int mb = (int)(hist[b * 2] + hist[b * 2 + 1]);
                        if (run + mb >= k) {
                            s_prefix = (unsigned)b; s_cntgt = run; s_total = run + mb; s_lvl = 0;
                            break;
                        }
                        run += mb;
                    }
                }
            }
            for (int level = 1; level <= 2; ++level) {
                __syncthreads();
                if (s_total <= CAP) break;
                for (int i = tid; i < 512; i += NTHR) hist[i] = 0;
                __syncthreads();
                unsigned pfx = s_prefix;
                const int msh = 32 - (12 + 8 * (level - 1));
                const int bsh = msh - 8;
                for (int i = tid; i < V4; i += NTHR) {
                    float4 l4 = row4[i];
                    float vv4[4] = { l4.x, l4.y, l4.z, l4.w };
                    #pragma unroll
                    for (int j = 0; j < 4; ++j) {
                        unsigned key = keyOf(vv4[j]);
                        if ((key >> msh) == pfx)
                            atomicAdd(&hist[(((key >> bsh) & 255u) << 1) | cpy], 1u);
                    }
                }
                for (int i = Vt + tid; i < V; i += NTHR) {
                    unsigned key = keyOf(row[i]);
                    if ((key >> msh) == pfx)
                        atomicAdd(&hist[(((key >> bsh) & 255u) << 1) | cpy], 1u);
                }
                __syncthreads();
                if (tid == 0) {
                    int run = s_cntgt;
                    for (int b = 255; b >= 0; --b) {
                        int mb = (int)(hist[b * 2] + hist[b * 2 + 1]);
                        if (run + mb >= k) {
                            s_prefix = (pfx << 8) | (unsigned)b; s_cntgt = run; s_total = run + mb;
                            break;
                        }
                        run += mb;
                    }
                    s_lvl = level;
                }
            }
            __syncthreads();
            unsigned tlo2 = s_prefix << (20 - 8 * s_lvl);
            float thrF2 = valOfKey(tlo2);
            if (tid == 0) s_ncand = 0;
            __syncthreads();
            {
                int i = tid;
                for (; i + 3 * NTHR < V4; i += 4 * NTHR) {
                    float4 a = row4[i];
                    float4 b = row4[i + NTHR];
                    float4 c = row4[i + 2 * NTHR];
                    float4 d = row4[i + 3 * NTHR];
                    SPEC1(a.x, i * 4 + 0, thrF2); SPEC1(a.y, i * 4 + 1, thrF2);
                    SPEC1(a.z, i * 4 + 2, thrF2); SPEC1(a.w, i * 4 + 3, thrF2);
                    SPEC1(b.x, (i + NTHR) * 4 + 0, thrF2); SPEC1(b.y, (i + NTHR) * 4 + 1, thrF2);
                    SPEC1(b.z, (i + NTHR) * 4 + 2, thrF2); SPEC1(b.w, (i + NTHR) * 4 + 3, thrF2);
                    SPEC1(c.x, (i + 2 * NTHR) * 4 + 0, thrF2); SPEC1(c.y, (i + 2 * NTHR) * 4 + 1, thrF2);
                    SPEC1(c.z, (i + 2 * NTHR) * 4 + 2, thrF2); SPEC1(c.w, (i + 2 * NTHR) * 4 + 3, thrF2);
                    SPEC1(d.x, (i + 3 * NTHR) * 4 + 0, thrF2); SPEC1(d.y, (i + 3 * NTHR) * 4 + 1, thrF2);
                    SPEC1(d.z, (i + 3 * NTHR) * 4 + 2, thrF2); SPEC1(d.w, (i + 3 * NTHR) * 4 + 3, thrF2);
                }
                for (; i < V4; i += NTHR) {
                    float4 a = row4[i];
                    SPEC1(a.x, i * 4 + 0, thrF2); SPEC1(a.y, i * 4 + 1, thrF2);
                    SPEC1(a.z, i * 4 + 2, thrF2); SPEC1(a.w, i * 4 + 3, thrF2);
                }
                for (int ii = Vt + tid; ii < V; ii += NTHR)
                    SPEC1(row[ii], ii, thrF2);
            }
            __syncthreads();
            ncand = s_ncand;
            if (ncand > CAP) ncand = CAP;
            if (k > ncand) k = ncand;
        }
    }
    if (k > ncand) k = ncand;                             // safety

    // ------- Phase 2.5: adaptive exact/near-exact refine (ncand > 1024) ------
    bool fromC2 = false;
    bool bigSort = false;
    if (ncand > SMALL) {
        unsigned pfx; int run; int bb;
        if (fastok) { pfx = 0u; run = 0; bb = 32; }
        else { pfx = s_prefix; run = s_cntgt; bb = 20 - 8 * s_lvl; }
        int totR = ncand;
        while (totR > SMALL - 16 && bb > 0) {
            int step = (bb >= 8) ? 8 : bb;
            bb -= step;
            int nbins = 1 << step;
            for (int i = tid; i < 16 * 257; i += NTHR) refHist[i] = 0;
            __syncthreads();
            {
                const int sh = bb + step;
                const unsigned lc = (unsigned)(lane & 15) * 257u;
                for (int i = tid; i < ncand; i += NTHR) {
                    unsigned key = (unsigned)(cand[i] >> 32);
                    bool in = (sh >= 32) || ((key >> sh) == pfx);
                    if (in)
                        atomicAdd(&refHist[lc + ((key >> bb) & (unsigned)(nbins - 1))], 1u);
                }
            }
            __syncthreads();
            int cnt = 0;
            if (tid < 256 && tid < nbins) {
                #pragma unroll
                for (int c = 0; c < 16; ++c) cnt += (int)refHist[c * 257 + tid];
            }
            int vv = cnt;
            #pragma unroll
            for (int d = 1; d < 64; d <<= 1) {
                int o = __shfl_down(vv, d);
                if (lane + d < 64) vv += o;
            }
            if (tid < 256 && lane == 0) wtotI[wid] = vv;
            __syncthreads();
            if (tid < 256) {
                int off = 0;
                for (int w = wid + 1; w < 4; ++w) off += wtotI[w];
                int incl = vv + off;
                int abv = incl - cnt;
                int kk = k - run;
                if (incl >= kk && abv < kk) {
                    s_prefix = (pfx << step) | (unsigned)tid;
                    s_cntgt = run + abv;
                    s_total = run + abv + cnt;
                }
            }
            __syncthreads();
            pfx = s_prefix;
            run = s_cntgt;
            totR = s_total;
        }
        unsigned tref0 = (bb > 0) ? (pfx << bb) : pfx;
        unsigned tref = (tref0 >= GUARD) ? (tref0 - GUARD) : 0u;
        if (tid == 0) s_nc2 = 0;
        __syncthreads();
        for (int i = tid; i < ncand; i += NTHR) {
            ull cv = cand[i];
            bool pred = ((unsigned)(cv >> 32) >= tref);
            ull mask = __ballot(pred ? 1 : 0);
            if (mask) {
                int leader = __ffsll(mask) - 1;
                int cnt2 = __popcll(mask);
                int bpos = 0;
                if (lane == leader) bpos = atomicAdd(&s_nc2, cnt2);
                bpos = __shfl(bpos, leader);
                if (pred) {
                    int pos = bpos + __popcll(mask & ((1ULL << lane) - 1ULL));
                    if (pos < SMALL) cand2[pos] = cv;
                }
            }
        }
        __syncthreads();
        int nc2 = s_nc2;
        if (nc2 <= SMALL) { ncand = nc2; fromC2 = true; }
        else bigSort = true;
    }

    // ---------------- Phase 3: descending sort -------------------------------
    if (!bigSort) {
        const ull* src = fromC2 ? cand2 : cand;
        ull v = (tid < ncand) ? src[tid] : 0ULL;
        int seg = 0;
        #pragma unroll
        for (int size = 2; size <= SMALL; size <<= 1) {
            #pragma unroll
            for (int stride = size >> 1; stride > 0; stride >>= 1) {
                ull o;
                if (stride < 64) {
                    o = shflXor64(v, stride);
                } else {
                    cand[seg * SMALL + tid] = v;
                    __syncthreads();
                    o = cand[seg * SMALL + (tid ^ stride)];
                    seg ^= 1;
                }
                bool takeMax = (((tid & size) == 0) == ((tid & stride) == 0));
                ull mx = (v > o) ? v : o;
                ull mn = (v > o) ? o : v;
                v = takeMax ? mx : mn;
            }
        }
        cand[tid] = v;
        varr[tid] = (tid < ncand) ? (valOfKey((unsigned)(v >> 32)) / t) : NEG_BIG;
        __syncthreads();
    } else {
        int P = 2; while (P < ncand) P <<= 1;
        for (int i = ncand + tid; i < P; i += NTHR) cand[i] = 0ULL;
        __syncthreads();
        for (int size = 2; size <= P; size <<= 1) {
            for (int stride = size >> 1; stride > 0; stride >>= 1) {
                for (int i = tid; i < P; i += NTHR) {
                    int j = i ^ stride;
                    if (j > i) {
                        ull a = cand[i], b = cand[j];
                        bool up = ((i & size) == 0);
                        bool sw = up ? (a < b) : (a > b);
                        if (sw) { cand[i] = b; cand[j] = a; }
                    }
                }
                __syncthreads();
            }
        }
        for (int i = tid; i < 1024; i += NTHR)
            varr[i] = (i < ncand) ? (valOfKey((unsigned)(cand[i] >> 32)) / t) : NEG_BIG;
        __syncthreads();
    }

    // ---------------- Phase 4: top-k/top-p/sample ----------------------------
    const float m = varr[0];
    const float tkeyV = varr[k - 1];
    int ntop = k;
    while (ntop < ncand) {
        float vi = (ntop < 1024) ? varr[ntop]
                                 : (valOfKey((unsigned)(cand[ntop] >> 32)) / t);
        if (vi != tkeyV) break;
        ++ntop;
    }
    if (ntop > 1024) ntop = 1024;

    {
        float e = (tid < ntop) ? expf(varr[tid] - m) : 0.0f;
        Earr[tid] = e;
        sfx[tid] = e;
        if (tid == 0) { s_nkeep = 0; s_rank = 0; s_amax = 0ULL; }
        if (tid < 64) bitmap[tid] = 0;
    }
    __syncthreads();
    {
        float* A = sfx;
        float* Bf = sfx2;
        #pragma unroll
        for (int d = 1; d < 1024; d <<= 1) {
            float t0 = (tid + d < 1024) ? A[tid + d] : 0.0f;
            Bf[tid] = A[tid] + t0;
            __syncthreads();
            float* tmp = A; A = Bf; Bf = tmp;
        }
    }
    const float Zp = sfx[0];
    const float cmp = 1.0f - p;
    {
        int local = 0;
        for (int i = tid; i < ntop; i += NTHR)
            if (sfx[i] / Zp > cmp) local++;
        #pragma unroll
        for (int d = 1; d < 64; d <<= 1) local += __shfl_xor(local, d);
        if (lane == 0 && local) atomicAdd(&s_nkeep, local);
    }
    __syncthreads();
    const int nkeep = s_nkeep;
    if (tid == 0) {
        float vb = varr[nkeep - 1];
        int g0 = nkeep - 1;
        while (g0 > 0 && varr[g0 - 1] == vb) --g0;
        int g1 = nkeep;
        while (g1 < ntop && varr[g1] == vb) ++g1;
        s_g0 = g0; s_g1 = g1;
    }
    __syncthreads();
    const int g0 = s_g0, g1 = s_g1;
    const int mkeep = nkeep - g0;
    for (int i = g0 + tid; i < g1; i += NTHR) {
        unsigned gi = ~(unsigned)(cand[i] & 0xFFFFFFFFull);
        int rk = 0;
        for (int j = g0; j < g1; ++j) {
            unsigned gj = ~(unsigned)(cand[j] & 0xFFFFFFFFull);
            if (gj > gi) rk++;
        }
        flagArr[i] = (rk < mkeep) ? 1 : 0;
    }
    __syncthreads();

    const float Z2 = (nkeep < 1024) ? (Zp - sfx[nkeep]) : Zp;
    const float L = logf(Z2);

    {
        ull lm = 0ULL;
        for (int i = tid; i < g1; i += NTHR) {
            if (i < g0 || flagArr[i]) {
                unsigned lo = (unsigned)(cand[i] & 0xFFFFFFFFull);
                unsigned gidx = ~lo;
                float u = urow[gidx];
                float q = -((u >= RMAX_F) ? RMAX_LOG_F : logf(u));
                float prob = Earr[i] / Z2;
                float ratio = greedy ? prob : (prob / q);
                ull comp = ((ull)__float_as_uint(ratio) << 32) | lo;
                if (comp > lm) lm = comp;
                if (gidx < 2048) atomicOr(&bitmap[gidx >> 5], 1u << (gidx & 31));
            }
        }
        #pragma unroll
        for (int d = 1; d < 64; d <<= 1) {
            ull o = shflXor64(lm, d);
            if (o > lm) lm = o;
        }
        if (lane == 0 && lm) atomicMax(&s_amax, lm);
    }
    __syncthreads();
    const unsigned samp_lo = (unsigned)(s_amax & 0xFFFFFFFFull);
    const unsigned samp = ~samp_lo;
    for (int i = tid; i < ntop; i += NTHR)
        if ((unsigned)(cand[i] & 0xFFFFFFFFull) == samp_lo) s_vs = varr[i];
    __syncthreads();
    const float lp_s = (s_vs - m) - L;
    {
        int local = 0;
        for (int i = tid; i < nkeep; i += NTHR)
            if ((varr[i] - m) - L > lp_s) local++;
        #pragma unroll
        for (int d = 1; d < 64; d <<= 1) local += __shfl_xor(local, d);
        if (lane == 0 && local) atomicAdd(&s_rank, local);
    }
    __syncthreads();

    // ---------------- Phase 5: outputs ---------------------------------------
    float* o_samp = out;
    float* o_idx  = out + B;
    float* o_lp   = out + B + (long long)B * (K + 1);
    float* o_rank = out + B + 2LL * B * (K + 1);
    const long long rowo = (long long)r * (K + 1);
    const int ntk = (nkeep < K) ? nkeep : K;

    if (tid < g1) {
        const int i = tid;
        bool kept = (i < g0) || flagArr[i];
        if (kept) {
            float v = varr[i];
            int rs, re, base;
            if (i >= g0) { rs = g0; re = g1; base = g0; }
            else {
                rs = i; while (rs > 0 && varr[rs - 1] == v) --rs;
                re = i + 1; while (re < g1 && varr[re] == v) ++re;
                base = rs;
            }
            if (base < ntk) {
                unsigned myidx = ~(unsigned)(cand[i] & 0xFFFFFFFFull);
                int cnt = 0;
                for (int j = rs; j < re; ++j) {
                    if (j == i) continue;
                    if (j >= g0 && !flagArr[j]) continue;
                    unsigned gj = ~(unsigned)(cand[j] & 0xFFFFFFFFull);
                    if (gj < myidx) cnt++;
                }
                int slot = base + cnt;
                if (slot < ntk) {
                    o_idx[rowo + 1 + slot] = (float)myidx;
                    o_lp[rowo + 1 + slot] = (v - m) - L;
                }
            }
        }
    }

    if (tid == 0) {
        o_samp[r] = (float)samp;
        o_idx[rowo] = (float)samp;
        o_lp[rowo] = lp_s;
        o_rank[r] = (float)s_rank;
        if (nkeep < K) {
            int j = 0;
            for (int c = nkeep; c < K; ++c) {
                while (bitmap[j >> 5] & (1u << (j & 31))) ++j;
                o_idx[rowo + 1 + c] = (float)j;
                o_lp[rowo + 1 + c] = NEG_BIG;
                ++j;
            }
        }
    }
}

extern "C" void kernel_launch(void* const* d_in, const int* in_sizes, int n_in,
                              void* d_out, int out_size, void* d_ws, size_t ws_size,
                              hipStream_t stream) {
    const float* logits      = (const float*)d_in[0];
    const float* temperature = (const float*)d_in[1];
    const int*   top_k       = (const int*)d_in[2];
    const float* top_p       = (const float*)d_in[3];
    const float* gumbel      = (const float*)d_in[4];
    int B = in_sizes[1];
    int V = in_sizes[0] / B;
    int K = (out_size / B - 4) / 2;

    // ws layout: [B*NS int cnt][B unsigned tlo][pad to 256][B*CAP ull cand]
    size_t cnt_bytes = (size_t)B * NS * sizeof(int);
    size_t tlo_off = cnt_bytes;
    size_t off = ((tlo_off + (size_t)B * 4) + 255) & ~(size_t)255;
    size_t need = off + (size_t)B * CAP * sizeof(ull);

    if (d_ws != nullptr && ws_size >= need) {
        int* ws_cnt = (int*)d_ws;
        unsigned* ws_tlo = (unsigned*)((char*)d_ws + tlo_off);
        ull* ws_cand = (ull*)((char*)d_ws + off);
        a0_thresh<<<B, NTHR, 0, stream>>>(logits, top_k, ws_tlo, B, V);
        a1_compact<<<B * NS, ATHR, 0, stream>>>(logits, ws_tlo, ws_cnt, ws_cand, B, V);
        sampler_tail<<<B, NTHR, 0, stream>>>(logits, temperature, top_k, top_p,
                                             gumbel, (float*)d_out, ws_cnt, ws_cand,
                                             B, V, K, 1);
    } else {
        sampler_tail<<<B, NTHR, 0, stream>>>(logits, temperature, top_k, top_p,
                                             gumbel, (float*)d_out, nullptr, nullptr,
                                             B, V, K, 0);
    }
}

// Round 6
// 275.707 us; speedup vs baseline: 2.2590x; 1.0126x over previous
//
#include <hip/hip_runtime.h>
#include <math.h>

#define NTHR 1024
#define CAP 8192
#define BINS 4096
#define SMALL 1024
#define GUARD 16u
#define SS 4096

#define RMAX_F 0.9999999403953552f
#define RMAX_LOG_F -5.960464477539063e-08f
#define NEG_BIG -3.0e38f

typedef unsigned long long ull;

__device__ __forceinline__ unsigned keyOf(float v) {
    unsigned b = __float_as_uint(v);
    return (b & 0x80000000u) ? ~b : (b | 0x80000000u);
}
__device__ __forceinline__ float valOfKey(unsigned k) {
    unsigned b = (k & 0x80000000u) ? (k ^ 0x80000000u) : ~k;
    return __uint_as_float(b);
}
__device__ __forceinline__ ull shflXor64(ull v, int m) {
    int lo = __shfl_xor((int)(unsigned)v, m);
    int hi = __shfl_xor((int)(unsigned)(v >> 32), m);
    return ((ull)(unsigned)hi << 32) | (unsigned)lo;
}

// ---------------------------------------------------------------------------
// R6: 2-way split at the SORT boundary (diagnostic + 8x-batched front loads).
//  R5 lesson: 3-way split cost ~14 us vs monolith (launch serialization, no
//  overlap). This split's purpose is attribution: front (select+sort) vs
//  tail (softmax/sample/emit) as separate rocprof rows. Coupling is 8 KB/row
//  (sorted 1024 cand) + {nc1,k} -> numerics bit-identical to R3.
//  sampler_mono (R3 verbatim) kept as no-ws fallback.
// ---------------------------------------------------------------------------

#define H4(v4) do { \
        atomicAdd(&hist[((keyOf((v4).x) >> 20) << 1) | cpy], 1u); \
        atomicAdd(&hist[((keyOf((v4).y) >> 20) << 1) | cpy], 1u); \
        atomicAdd(&hist[((keyOf((v4).z) >> 20) << 1) | cpy], 1u); \
        atomicAdd(&hist[((keyOf((v4).w) >> 20) << 1) | cpy], 1u); \
    } while (0)

#define SPEC1(val, gidx_, thr_) do { \
        float _v = (val); \
        if (_v >= (thr_)) { \
            int _pos = atomicAdd(&s_ncand, 1); \
            if (_pos < CAP) \
                cand[_pos] = ((ull)keyOf(_v) << 32) | (unsigned)(~(unsigned)(gidx_)); \
        } \
    } while (0)

#define SPEC4(v4, i4, thr_) do { \
        SPEC1((v4).x, (i4) * 4 + 0, thr_); SPEC1((v4).y, (i4) * 4 + 1, thr_); \
        SPEC1((v4).z, (i4) * 4 + 2, thr_); SPEC1((v4).w, (i4) * 4 + 3, thr_); \
    } while (0)

// ================= FRONT: select + sort -> ws ==============================
__global__ __launch_bounds__(NTHR) void sampler_front(
    const float* __restrict__ logits,
    const int* __restrict__ top_kv,
    ull* __restrict__ ws_srt,
    int* __restrict__ ws_meta,
    int B, int V)
{
    const int r = blockIdx.x;
    const int tid = threadIdx.x;
    const int lane = tid & 63;
    const int wid = tid >> 6;

    __shared__ ull cand[CAP];                     // 64 KB; aliased as hist
    __shared__ ull cand2[SMALL];                  // 8 KB
    __shared__ unsigned refHist[16 * 257];        // 16.4 KB
    __shared__ int wtotI[16];
    __shared__ unsigned s_prefix;
    __shared__ int s_cntgt, s_total, s_lvl;
    __shared__ int s_ncand, s_nc2;

    unsigned* hist = (unsigned*)cand;

    const float* row = logits + (long long)r * V;
    const float4* row4 = (const float4*)row;
    const int V4 = V >> 2;
    const int Vt = V4 << 2;
    const unsigned cpy = tid & 1u;

    int k = top_kv[r];
    if (k < 1) k = 1;
    if (k > V) k = V;

    // ------------- P0: subsample -> speculative threshold -------------------
    for (int i = tid; i < BINS * 2; i += NTHR) hist[i] = 0;
    __syncthreads();
    {
        int f4pos = (int)(((long long)tid * V4) >> 10);
        float4 sv = row4[f4pos];
        H4(sv);
    }
    __syncthreads();
    int ts;
    {
        int tc = 2 * k + 400;
        if (tc > 2400) tc = 2400;
        if (tc < 600) tc = 600;
        ts = (int)(((long long)tc * SS + V - 1) / V);
        if (ts < 4) ts = 4;
    }
    {
        int base = tid << 2;
        int cs = 0;
        #pragma unroll
        for (int j = 0; j < 4; ++j)
            cs += (int)(hist[(base + j) * 2] + hist[(base + j) * 2 + 1]);
        int vv = cs;
        #pragma unroll
        for (int d = 1; d < 64; d <<= 1) {
            int o = __shfl_down(vv, d);
            if (lane + d < 64) vv += o;
        }
        if (lane == 0) wtotI[wid] = vv;
        __syncthreads();
        int off = 0;
        for (int w = wid + 1; w < 16; ++w) off += wtotI[w];
        int mine = vv + off;
        int above = mine - cs;
        if (mine >= ts && above < ts) {                   // exactly one thread
            int run = above;
            for (int b = base + 3; b >= base; --b) {
                int mb = (int)(hist[b * 2] + hist[b * 2 + 1]);
                if (run + mb >= ts) { s_prefix = (unsigned)b; break; }
                run += mb;
            }
        }
        if (tid == 0) s_ncand = 0;
        __syncthreads();
    }
    unsigned tlo = s_prefix << 20;
    float thrF = valOfKey(tlo);

    // ------------- P1: single-pass speculative compaction (8x batch) --------
    {
        int i = tid;
        for (; i + 7 * NTHR < V4; i += 8 * NTHR) {
            float4 a = row4[i];
            float4 b = row4[i + NTHR];
            float4 c = row4[i + 2 * NTHR];
            float4 d = row4[i + 3 * NTHR];
            float4 e = row4[i + 4 * NTHR];
            float4 f = row4[i + 5 * NTHR];
            float4 g = row4[i + 6 * NTHR];
            float4 h = row4[i + 7 * NTHR];
            SPEC4(a, i, thrF); SPEC4(b, i + NTHR, thrF);
            SPEC4(c, i + 2 * NTHR, thrF); SPEC4(d, i + 3 * NTHR, thrF);
            SPEC4(e, i + 4 * NTHR, thrF); SPEC4(f, i + 5 * NTHR, thrF);
            SPEC4(g, i + 6 * NTHR, thrF); SPEC4(h, i + 7 * NTHR, thrF);
        }
        for (; i < V4; i += NTHR) {
            float4 a = row4[i];
            SPEC4(a, i, thrF);
        }
        for (int ii = Vt + tid; ii < V; ii += NTHR)
            SPEC1(row[ii], ii, thrF);
    }
    __syncthreads();
    int ncand = s_ncand;
    bool fastok = (ncand >= k && ncand <= CAP);

    // ------------- exact two-pass fallback ----------------------------------
    if (!fastok) {
        for (int i = tid; i < BINS * 2; i += NTHR) hist[i] = 0;
        __syncthreads();
        {
            int i = tid;
            for (; i + 3 * NTHR < V4; i += 4 * NTHR) {
                float4 a = row4[i];
                float4 b = row4[i + NTHR];
                float4 c = row4[i + 2 * NTHR];
                float4 d = row4[i + 3 * NTHR];
                H4(a); H4(b); H4(c); H4(d);
            }
            for (; i < V4; i += NTHR) { float4 a = row4[i]; H4(a); }
            for (int ii = Vt + tid; ii < V; ii += NTHR)
                atomicAdd(&hist[((keyOf(row[ii]) >> 20) << 1) | cpy], 1u);
        }
        __syncthreads();
        {
            int base = tid << 2;
            int cs = 0;
            #pragma unroll
            for (int j = 0; j < 4; ++j)
                cs += (int)(hist[(base + j) * 2] + hist[(base + j) * 2 + 1]);
            int vv = cs;
            #pragma unroll
            for (int d = 1; d < 64; d <<= 1) {
                int o = __shfl_down(vv, d);
                if (lane + d < 64) vv += o;
            }
            if (lane == 0) wtotI[wid] = vv;
            __syncthreads();
            int off = 0;
            for (int w = wid + 1; w < 16; ++w) off += wtotI[w];
            int mine = vv + off;
            int above = mine - cs;
            if (mine >= k && above < k) {
                int run = above;
                for (int b = base + 3; b >= base; --b) {
                    int mb = (int)(hist[b * 2] + hist[b * 2 + 1]);
                    if (run + mb >= k) {
                        s_prefix = (unsigned)b; s_cntgt = run; s_total = run + mb; s_lvl = 0;
                        break;
                    }
                    run += mb;
                }
            }
        }
        for (int level = 1; level <= 2; ++level) {
            __syncthreads();
            if (s_total <= CAP) break;
            for (int i = tid; i < 512; i += NTHR) hist[i] = 0;
            __syncthreads();
            unsigned pfx = s_prefix;
            const int msh = 32 - (12 + 8 * (level - 1));
            const int bsh = msh - 8;
            for (int i = tid; i < V4; i += NTHR) {
                float4 l4 = row4[i];
                float vv4[4] = { l4.x, l4.y, l4.z, l4.w };
                #pragma unroll
                for (int j = 0; j < 4; ++j) {
                    unsigned key = keyOf(vv4[j]);
                    if ((key >> msh) == pfx)
                        atomicAdd(&hist[(((key >> bsh) & 255u) << 1) | cpy], 1u);
                }
            }
            for (int i = Vt + tid; i < V; i += NTHR) {
                unsigned key = keyOf(row[i]);
                if ((key >> msh) == pfx)
                    atomicAdd(&hist[(((key >> bsh) & 255u) << 1) | cpy], 1u);
            }
            __syncthreads();
            if (tid == 0) {
                int run = s_cntgt;
                for (int b = 255; b >= 0; --b) {
                    int mb = (int)(hist[b * 2] + hist[b * 2 + 1]);
                    if (run + mb >= k) {
                        s_prefix = (pfx << 8) | (unsigned)b; s_cntgt = run; s_total = run + mb;
                        break;
                    }
                    run += mb;
                }
                s_lvl = level;
            }
        }
        __syncthreads();
        unsigned tlo2 = s_prefix << (20 - 8 * s_lvl);
        float thrF2 = valOfKey(tlo2);
        tlo = tlo2;
        if (tid == 0) s_ncand = 0;
        __syncthreads();
        {
            int i = tid;
            for (; i + 3 * NTHR < V4; i += 4 * NTHR) {
                float4 a = row4[i];
                float4 b = row4[i + NTHR];
                float4 c = row4[i + 2 * NTHR];
                float4 d = row4[i + 3 * NTHR];
                SPEC4(a, i, thrF2); SPEC4(b, i + NTHR, thrF2);
                SPEC4(c, i + 2 * NTHR, thrF2); SPEC4(d, i + 3 * NTHR, thrF2);
            }
            for (; i < V4; i += NTHR) {
                float4 a = row4[i];
                SPEC4(a, i, thrF2);
            }
            for (int ii = Vt + tid; ii < V; ii += NTHR)
                SPEC1(row[ii], ii, thrF2);
        }
        __syncthreads();
        ncand = s_ncand;
        if (ncand > CAP) ncand = CAP;
        if (k > ncand) k = ncand;
    }
    if (k > ncand) k = ncand;
    if (k < 1) k = 1;

    // ------- refine + recompact (ncand > 1024) ------------------------------
    bool fromC2 = false;
    bool bigSort = false;
    if (ncand > SMALL) {
        unsigned pfx; int run; int bb;
        if (fastok) { pfx = 0u; run = 0; bb = 32; }
        else { pfx = s_prefix; run = s_cntgt; bb = 20 - 8 * s_lvl; }
        int totR = ncand;
        while (totR > SMALL - 16 && bb > 0) {
            int step = (bb >= 8) ? 8 : bb;
            bb -= step;
            int nbins = 1 << step;
            for (int i = tid; i < 16 * 257; i += NTHR) refHist[i] = 0;
            __syncthreads();
            {
                const int sh = bb + step;
                const unsigned lc = (unsigned)(lane & 15) * 257u;
                for (int i = tid; i < ncand; i += NTHR) {
                    unsigned key = (unsigned)(cand[i] >> 32);
                    bool in = (sh >= 32) || ((key >> sh) == pfx);
                    if (in)
                        atomicAdd(&refHist[lc + ((key >> bb) & (unsigned)(nbins - 1))], 1u);
                }
            }
            __syncthreads();
            int cnt = 0;
            if (tid < 256 && tid < nbins) {
                #pragma unroll
                for (int c = 0; c < 16; ++c) cnt += (int)refHist[c * 257 + tid];
            }
            int vv = cnt;
            #pragma unroll
            for (int d = 1; d < 64; d <<= 1) {
                int o = __shfl_down(vv, d);
                if (lane + d < 64) vv += o;
            }
            if (tid < 256 && lane == 0) wtotI[wid] = vv;
            __syncthreads();
            if (tid < 256) {
                int off = 0;
                for (int w = wid + 1; w < 4; ++w) off += wtotI[w];
                int incl = vv + off;
                int abv = incl - cnt;
                int kk = k - run;
                if (incl >= kk && abv < kk) {
                    s_prefix = (pfx << step) | (unsigned)tid;
                    s_cntgt = run + abv;
                    s_total = run + abv + cnt;
                }
            }
            __syncthreads();
            pfx = s_prefix;
            run = s_cntgt;
            totR = s_total;
        }
        unsigned tref0 = (bb > 0) ? (pfx << bb) : pfx;
        unsigned tref = (tref0 >= GUARD) ? (tref0 - GUARD) : 0u;
        if (tid == 0) s_nc2 = 0;
        __syncthreads();
        for (int i = tid; i < ncand; i += NTHR) {
            ull cv = cand[i];
            bool pred = ((unsigned)(cv >> 32) >= tref);
            ull mask = __ballot(pred ? 1 : 0);
            if (mask) {
                int leader = __ffsll(mask) - 1;
                int cnt2 = __popcll(mask);
                int bpos = 0;
                if (lane == leader) bpos = atomicAdd(&s_nc2, cnt2);
                bpos = __shfl(bpos, leader);
                if (pred) {
                    int pos = bpos + __popcll(mask & ((1ULL << lane) - 1ULL));
                    if (pos < SMALL) cand2[pos] = cv;
                }
            }
        }
        __syncthreads();
        int nc2 = s_nc2;
        if (nc2 <= SMALL) { ncand = nc2; fromC2 = true; }
        else bigSort = true;
    }

    // ------- descending sort + ws write -------------------------------------
    ull outv;
    if (!bigSort) {
        const ull* src = fromC2 ? cand2 : cand;
        ull v = (tid < ncand) ? src[tid] : 0ULL;
        int seg = 0;
        #pragma unroll
        for (int size = 2; size <= SMALL; size <<= 1) {
            #pragma unroll
            for (int stride = size >> 1; stride > 0; stride >>= 1) {
                ull o;
                if (stride < 64) {
                    o = shflXor64(v, stride);
                } else {
                    cand[seg * SMALL + tid] = v;
                    __syncthreads();
                    o = cand[seg * SMALL + (tid ^ stride)];
                    seg ^= 1;
                }
                bool takeMax = (((tid & size) == 0) == ((tid & stride) == 0));
                ull mx = (v > o) ? v : o;
                ull mn = (v > o) ? o : v;
                v = takeMax ? mx : mn;
            }
        }
        outv = v;
    } else {
        int P = 2; while (P < ncand) P <<= 1;
        for (int i = ncand + tid; i < P; i += NTHR) cand[i] = 0ULL;
        __syncthreads();
        for (int size = 2; size <= P; size <<= 1) {
            for (int stride = size >> 1; stride > 0; stride >>= 1) {
                for (int i = tid; i < P; i += NTHR) {
                    int j = i ^ stride;
                    if (j > i) {
                        ull a = cand[i], b = cand[j];
                        bool up = ((i & size) == 0);
                        bool sw = up ? (a < b) : (a > b);
                        if (sw) { cand[i] = b; cand[j] = a; }
                    }
                }
                __syncthreads();
            }
        }
        outv = cand[tid];
    }
    ws_srt[(size_t)r * SMALL + tid] = outv;
    if (tid == 0) {
        int nc1 = (ncand < SMALL) ? ncand : SMALL;
        ws_meta[2 * r] = nc1;
        ws_meta[2 * r + 1] = k;
    }
}

// ================= FINISH: softmax/top-p/sample/emit =======================
__global__ __launch_bounds__(NTHR) void sampler_finish(
    const float* __restrict__ temperature,
    const float* __restrict__ top_pv,
    const float* __restrict__ gumbel,
    float* __restrict__ out,
    const ull* __restrict__ ws_srt,
    const int* __restrict__ ws_meta,
    int B, int V, int K)
{
    const int r = blockIdx.x;
    const int tid = threadIdx.x;
    const int lane = tid & 63;

    __shared__ ull cand[SMALL];                   // 8 KB sorted candidates
    __shared__ float varr[1024];
    __shared__ float Earr[1024];
    __shared__ float sfx[1024];
    __shared__ float sfx2[1024];
    __shared__ unsigned char flagArr[1024];
    __shared__ unsigned bitmap[64];
    __shared__ int s_nkeep, s_rank, s_g0, s_g1;
    __shared__ ull s_amax;
    __shared__ float s_vs;

    const float* urow = gumbel + (long long)r * V;

    float traw = temperature[r];
    bool greedy = traw < 1e-5f;
    float t = greedy ? 1.0f : traw;
    float p = top_pv[r];
    const int nc1 = ws_meta[2 * r];
    const int k = ws_meta[2 * r + 1];

    {
        ull v = ws_srt[(size_t)r * SMALL + tid];
        cand[tid] = v;
        varr[tid] = (tid < nc1) ? (valOfKey((unsigned)(v >> 32)) / t) : NEG_BIG;
    }
    __syncthreads();

    const float m = varr[0];
    const float tkeyV = varr[k - 1];
    int ntop = k;
    while (ntop < nc1) {
        float vi = varr[ntop];
        if (vi != tkeyV) break;
        ++ntop;
    }

    {
        float e = (tid < ntop) ? expf(varr[tid] - m) : 0.0f;
        Earr[tid] = e;
        sfx[tid] = e;
        if (tid == 0) { s_nkeep = 0; s_rank = 0; s_amax = 0ULL; }
        if (tid < 64) bitmap[tid] = 0;
    }
    __syncthreads();
    {
        float* A = sfx;
        float* Bf = sfx2;
        #pragma unroll
        for (int d = 1; d < 1024; d <<= 1) {
            float t0 = (tid + d < 1024) ? A[tid + d] : 0.0f;
            Bf[tid] = A[tid] + t0;
            __syncthreads();
            float* tmp = A; A = Bf; Bf = tmp;
        }
    }
    const float Zp = sfx[0];
    const float cmp = 1.0f - p;
    {
        int local = 0;
        for (int i = tid; i < ntop; i += NTHR)
            if (sfx[i] / Zp > cmp) local++;
        #pragma unroll
        for (int d = 1; d < 64; d <<= 1) local += __shfl_xor(local, d);
        if (lane == 0 && local) atomicAdd(&s_nkeep, local);
    }
    __syncthreads();
    const int nkeep = s_nkeep;
    if (tid == 0) {
        float vb = varr[nkeep - 1];
        int g0 = nkeep - 1;
        while (g0 > 0 && varr[g0 - 1] == vb) --g0;
        int g1 = nkeep;
        while (g1 < ntop && varr[g1] == vb) ++g1;
        s_g0 = g0; s_g1 = g1;
    }
    __syncthreads();
    const int g0 = s_g0, g1 = s_g1;
    const int mkeep = nkeep - g0;
    for (int i = g0 + tid; i < g1; i += NTHR) {
        unsigned gi = ~(unsigned)(cand[i] & 0xFFFFFFFFull);
        int rk = 0;
        for (int j = g0; j < g1; ++j) {
            unsigned gj = ~(unsigned)(cand[j] & 0xFFFFFFFFull);
            if (gj > gi) rk++;
        }
        flagArr[i] = (rk < mkeep) ? 1 : 0;
    }
    __syncthreads();

    const float Z2 = (nkeep < 1024) ? (Zp - sfx[nkeep]) : Zp;
    const float L = logf(Z2);

    {
        ull lm = 0ULL;
        for (int i = tid; i < g1; i += NTHR) {
            if (i < g0 || flagArr[i]) {
                unsigned lo = (unsigned)(cand[i] & 0xFFFFFFFFull);
                unsigned gidx = ~lo;
                float u = urow[gidx];
                float q = -((u >= RMAX_F) ? RMAX_LOG_F : logf(u));
                float prob = Earr[i] / Z2;
                float ratio = greedy ? prob : (prob / q);
                ull comp = ((ull)__float_as_uint(ratio) << 32) | lo;
                if (comp > lm) lm = comp;
                if (gidx < 2048) atomicOr(&bitmap[gidx >> 5], 1u << (gidx & 31));
            }
        }
        #pragma unroll
        for (int d = 1; d < 64; d <<= 1) {
            ull o = shflXor64(lm, d);
            if (o > lm) lm = o;
        }
        if (lane == 0 && lm) atomicMax(&s_amax, lm);
    }
    __syncthreads();
    const unsigned samp_lo = (unsigned)(s_amax & 0xFFFFFFFFull);
    const unsigned samp = ~samp_lo;
    for (int i = tid; i < ntop; i += NTHR)
        if ((unsigned)(cand[i] & 0xFFFFFFFFull) == samp_lo) s_vs = varr[i];
    __syncthreads();
    const float lp_s = (s_vs - m) - L;
    {
        int local = 0;
        for (int i = tid; i < nkeep; i += NTHR)
            if ((varr[i] - m) - L > lp_s) local++;
        #pragma unroll
        for (int d = 1; d < 64; d <<= 1) local += __shfl_xor(local, d);
        if (lane == 0 && local) atomicAdd(&s_rank, local);
    }
    __syncthreads();

    float* o_samp = out;
    float* o_idx  = out + B;
    float* o_lp   = out + B + (long long)B * (K + 1);
    float* o_rank = out + B + 2LL * B * (K + 1);
    const long long rowo = (long long)r * (K + 1);
    const int ntk = (nkeep < K) ? nkeep : K;

    if (tid < g1) {
        const int i = tid;
        bool kept = (i < g0) || flagArr[i];
        if (kept) {
            float v = varr[i];
            int rs, re, base;
            if (i >= g0) { rs = g0; re = g1; base = g0; }
            else {
                rs = i; while (rs > 0 && varr[rs - 1] == v) --rs;
                re = i + 1; while (re < g1 && varr[re] == v) ++re;
                base = rs;
            }
            if (base < ntk) {
                unsigned myidx = ~(unsigned)(cand[i] & 0xFFFFFFFFull);
                int cnt = 0;
                for (int j = rs; j < re; ++j) {
                    if (j == i) continue;
                    if (j >= g0 && !flagArr[j]) continue;
                    unsigned gj = ~(unsigned)(cand[j] & 0xFFFFFFFFull);
                    if (gj < myidx) cnt++;
                }
                int slot = base + cnt;
                if (slot < ntk) {
                    o_idx[rowo + 1 + slot] = (float)myidx;
                    o_lp[rowo + 1 + slot] = (v - m) - L;
                }
            }
        }
    }

    if (tid == 0) {
        o_samp[r] = (float)samp;
        o_idx[rowo] = (float)samp;
        o_lp[rowo] = lp_s;
        o_rank[r] = (float)s_rank;
        if (nkeep < K) {
            int j = 0;
            for (int c = nkeep; c < K; ++c) {
                while (bitmap[j >> 5] & (1u << (j & 31))) ++j;
                o_idx[rowo + 1 + c] = (float)j;
                o_lp[rowo + 1 + c] = NEG_BIG;
                ++j;
            }
        }
    }
}

// ================= MONO: R3 monolith (no-ws fallback) ======================
__global__ __launch_bounds__(NTHR) void sampler_mono(
    const float* __restrict__ logits,
    const float* __restrict__ temperature,
    const int* __restrict__ top_kv,
    const float* __restrict__ top_pv,
    const float* __restrict__ gumbel,
    float* __restrict__ out,
    int B, int V, int K)
{
    const int r = blockIdx.x;
    const int tid = threadIdx.x;
    const int lane = tid & 63;
    const int wid = tid >> 6;

    __shared__ ull cand[CAP];
    __shared__ ull cand2[SMALL];
    __shared__ unsigned refHist[16 * 257];
    __shared__ int wtotI[16];
    __shared__ float varr[1024];
    __shared__ float Earr[1024];
    __shared__ float sfx[1024];
    __shared__ float sfx2[1024];
    __shared__ unsigned char flagArr[1024];
    __shared__ unsigned bitmap[64];
    __shared__ unsigned s_prefix;
    __shared__ int s_cntgt, s_total, s_lvl;
    __shared__ int s_ncand, s_nc2, s_nkeep, s_rank, s_g0, s_g1;
    __shared__ ull s_amax;
    __shared__ float s_vs;

    unsigned* hist = (unsigned*)cand;

    const float* row = logits + (long long)r * V;
    const float* urow = gumbel + (long long)r * V;

    float traw = temperature[r];
    bool greedy = traw < 1e-5f;
    float t = greedy ? 1.0f : traw;
    int k = top_kv[r];
    if (k < 1) k = 1;
    if (k > V) k = V;
    float p = top_pv[r];

    const float4* row4 = (const float4*)row;
    const int V4 = V >> 2;
    const int Vt = V4 << 2;
    const unsigned cpy = tid & 1u;

    for (int i = tid; i < BINS * 2; i += NTHR) hist[i] = 0;
    __syncthreads();
    {
        int f4pos = (int)(((long long)tid * V4) >> 10);
        float4 sv = row4[f4pos];
        H4(sv);
    }
    __syncthreads();
    int ts;
    {
        int tc = 2 * k + 400;
        if (tc > 2400) tc = 2400;
        if (tc < 600) tc = 600;
        ts = (int)(((long long)tc * SS + V - 1) / V);
        if (ts < 4) ts = 4;
    }
    {
        int base = tid << 2;
        int cs = 0;
        #pragma unroll
        for (int j = 0; j < 4; ++j)
            cs += (int)(hist[(base + j) * 2] + hist[(base + j) * 2 + 1]);
        int vv = cs;
        #pragma unroll
        for (int d = 1; d < 64; d <<= 1) {
            int o = __shfl_down(vv, d);
            if (lane + d < 64) vv += o;
        }
        if (lane == 0) wtotI[wid] = vv;
        __syncthreads();
        int off = 0;
        for (int w = wid + 1; w < 16; ++w) off += wtotI[w];
        int mine = vv + off;
        int above = mine - cs;
        if (mine >= ts && above < ts) {
            int run = above;
            for (int b = base + 3; b >= base; --b) {
                int mb = (int)(hist[b * 2] + hist[b * 2 + 1]);
                if (run + mb >= ts) { s_prefix = (unsigned)b; break; }
                run += mb;
            }
        }
        if (tid == 0) s_ncand = 0;
        __syncthreads();
    }
    unsigned tlo = s_prefix << 20;
    float thrF = valOfKey(tlo);

    {
        int i = tid;
        for (; i + 3 * NTHR < V4; i += 4 * NTHR) {
            float4 a = row4[i];
            float4 b = row4[i + NTHR];
            float4 c = row4[i + 2 * NTHR];
            float4 d = row4[i + 3 * NTHR];
            SPEC4(a, i, thrF); SPEC4(b, i + NTHR, thrF);
            SPEC4(c, i + 2 * NTHR, thrF); SPEC4(d, i + 3 * NTHR, thrF);
        }
        for (; i < V4; i += NTHR) {
            float4 a = row4[i];
            SPEC4(a, i, thrF);
        }
        for (int ii = Vt + tid; ii < V; ii += NTHR)
            SPEC1(row[ii], ii, thrF);
    }
    __syncthreads();
    int ncand = s_ncand;
    bool fastok = (ncand >= k && ncand <= CAP);

    if (!fastok) {
        for (int i = tid; i < BINS * 2; i += NTHR) hist[i] = 0;
        __syncthreads();
        {
            int i = tid;
            for (; i + 3 * NTHR < V4; i += 4 * NTHR) {
                float4 a = row4[i];
                float4 b = row4[i + NTHR];
                float4 c = row4[i + 2 * NTHR];
                float4 d = row4[i + 3 * NTHR];
                H4(a); H4(b); H4(c); H4(d);
            }
            for (; i < V4; i += NTHR) { float4 a = row4[i]; H4(a); }
            for (int ii = Vt + tid; ii < V; ii += NTHR)
                atomicAdd(&hist[((keyOf(row[ii]) >> 20) << 1) | cpy], 1u);
        }
        __syncthreads();
        {
            int base = tid << 2;
            int cs = 0;
            #pragma unroll
            for (int j = 0; j < 4; ++j)
                cs += (int)(hist[(base + j) * 2] + hist[(base + j) * 2 + 1]);
            int vv = cs;
            #pragma unroll
            for (int d = 1; d < 64; d <<= 1) {
                int o = __shfl_down(vv, d);
                if (lane + d < 64) vv += o;
            }
            if (lane == 0) wtotI[wid] = vv;
            __syncthreads();
            int off = 0;
            for (int w = wid + 1; w < 16; ++w) off += wtotI[w];
            int mine = vv + off;
            int above = mine - cs;
            if (mine >= k && above < k) {
                int run = above;
                for (int b = base + 3; b >= base; --b) {
                    int mb = (int)(hist[b * 2] + hist[b * 2 + 1]);
                    if (run + mb >= k) {
                        s_prefix = (unsigned)b; s_cntgt = run; s_total = run + mb; s_lvl = 0;
                        break;
                    }
                    run += mb;
                }
            }
        }
        for (int level = 1; level <= 2; ++level) {
            __syncthreads();
            if (s_total <= CAP) break;
            for (int i = tid; i < 512; i += NTHR) hist[i] = 0;
            __syncthreads();
            unsigned pfx = s_prefix;
            const int msh = 32 - (12 + 8 * (level - 1));
            const int bsh = msh - 8;
            for (int i = tid; i < V4; i += NTHR) {
                float4 l4 = row4[i];
                float vv4[4] = { l4.x, l4.y, l4.z, l4.w };
                #pragma unroll
                for (int j = 0; j < 4; ++j) {
                    unsigned key = keyOf(vv4[j]);
                    if ((key >> msh) == pfx)
                        atomicAdd(&hist[(((key >> bsh) & 255u) << 1) | cpy], 1u);
                }
            }
            for (int i = Vt + tid; i < V; i += NTHR) {
                unsigned key = keyOf(row[i]);
                if ((key >> msh) == pfx)
                    atomicAdd(&hist[(((key >> bsh) & 255u) << 1) | cpy], 1u);
            }
            __syncthreads();
            if (tid == 0) {
                int run = s_cntgt;
                for (int b = 255; b >= 0; --b) {
                    int mb = (int)(hist[b * 2] + hist[b * 2 + 1]);
                    if (run + mb >= k) {
                        s_prefix = (pfx << 8) | (unsigned)b; s_cntgt = run; s_total = run + mb;
                        break;
                    }
                    run += mb;
                }
                s_lvl = level;
            }
        }
        __syncthreads();
        unsigned tlo2 = s_prefix << (20 - 8 * s_lvl);
        float thrF2 = valOfKey(tlo2);
        tlo = tlo2;
        if (tid == 0) s_ncand = 0;
        __syncthreads();
        {
            int i = tid;
            for (; i + 3 * NTHR < V4; i += 4 * NTHR) {
                float4 a = row4[i];
                float4 b = row4[i + NTHR];
                float4 c = row4[i + 2 * NTHR];
                float4 d = row4[i + 3 * NTHR];
                SPEC4(a, i, thrF2); SPEC4(b, i + NTHR, thrF2);
                SPEC4(c, i + 2 * NTHR, thrF2); SPEC4(d, i + 3 * NTHR, thrF2);
            }
            for (; i < V4; i += NTHR) {
                float4 a = row4[i];
                SPEC4(a, i, thrF2);
            }
            for (int ii = Vt + tid; ii < V; ii += NTHR)
                SPEC1(row[ii], ii, thrF2);
        }
        __syncthreads();
        ncand = s_ncand;
        if (ncand > CAP) ncand = CAP;
        if (k > ncand) k = ncand;
    }
    if (k > ncand) k = ncand;

    bool fromC2 = false;
    bool bigSort = false;
    if (ncand > SMALL) {
        unsigned pfx; int run; int bb;
        if (fastok) { pfx = 0u; run = 0; bb = 32; }
        else { pfx = s_prefix; run = s_cntgt; bb = 20 - 8 * s_lvl; }
        int totR = ncand;
        while (totR > SMALL - 16 && bb > 0) {
            int step = (bb >= 8) ? 8 : bb;
            bb -= step;
            int nbins = 1 << step;
            for (int i = tid; i < 16 * 257; i += NTHR) refHist[i] = 0;
            __syncthreads();
            {
                const int sh = bb + step;
                const unsigned lc = (unsigned)(lane & 15) * 257u;
                for (int i = tid; i < ncand; i += NTHR) {
                    unsigned key = (unsigned)(cand[i] >> 32);
                    bool in = (sh >= 32) || ((key >> sh) == pfx);
                    if (in)
                        atomicAdd(&refHist[lc + ((key >> bb) & (unsigned)(nbins - 1))], 1u);
                }
            }
            __syncthreads();
            int cnt = 0;
            if (tid < 256 && tid < nbins) {
                #pragma unroll
                for (int c = 0; c < 16; ++c) cnt += (int)refHist[c * 257 + tid];
            }
            int vv = cnt;
            #pragma unroll
            for (int d = 1; d < 64; d <<= 1) {
                int o = __shfl_down(vv, d);
                if (lane + d < 64) vv += o;
            }
            if (tid < 256 && lane == 0) wtotI[wid] = vv;
            __syncthreads();
            if (tid < 256) {
                int off = 0;
                for (int w = wid + 1; w < 4; ++w) off += wtotI[w];
                int incl = vv + off;
                int abv = incl - cnt;
                int kk = k - run;
                if (incl >= kk && abv < kk) {
                    s_prefix = (pfx << step) | (unsigned)tid;
                    s_cntgt = run + abv;
                    s_total = run + abv + cnt;
                }
            }
            __syncthreads();
            pfx = s_prefix;
            run = s_cntgt;
            totR = s_total;
        }
        unsigned tref0 = (bb > 0) ? (pfx << bb) : pfx;
        unsigned tref = (tref0 >= GUARD) ? (tref0 - GUARD) : 0u;
        if (tid == 0) s_nc2 = 0;
        __syncthreads();
        for (int i = tid; i < ncand; i += NTHR) {
            ull cv = cand[i];
            bool pred = ((unsigned)(cv >> 32) >= tref);
            ull mask = __ballot(pred ? 1 : 0);
            if (mask) {
                int leader = __ffsll(mask) - 1;
                int cnt2 = __popcll(mask);
                int bpos = 0;
                if (lane == leader) bpos = atomicAdd(&s_nc2, cnt2);
                bpos = __shfl(bpos, leader);
                if (pred) {
                    int pos = bpos + __popcll(mask & ((1ULL << lane) - 1ULL));
                    if (pos < SMALL) cand2[pos] = cv;
                }
            }
        }
        __syncthreads();
        int nc2 = s_nc2;
        if (nc2 <= SMALL) { ncand = nc2; fromC2 = true; }
        else bigSort = true;
    }

    if (!bigSort) {
        const ull* src = fromC2 ? cand2 : cand;
        ull v = (tid < ncand) ? src[tid] : 0ULL;
        int seg = 0;
        #pragma unroll
        for (int size = 2; size <= SMALL; size <<= 1) {
            #pragma unroll
            for (int stride = size >> 1; stride > 0; stride >>= 1) {
                ull o;
                if (stride < 64) {
                    o = shflXor64(v, stride);
                } else {
                    cand[seg * SMALL + tid] = v;
                    __syncthreads();
                    o = cand[seg * SMALL + (tid ^ stride)];
                    seg ^= 1;
                }
                bool takeMax = (((tid & size) == 0) == ((tid & stride) == 0));
                ull mx = (v > o) ? v : o;
                ull mn = (v > o) ? o : v;
                v = takeMax ? mx : mn;
            }
        }
        cand[tid] = v;
        varr[tid] = (tid < ncand) ? (valOfKey((unsigned)(v >> 32)) / t) : NEG_BIG;
        __syncthreads();
    } else {
        int P = 2; while (P < ncand) P <<= 1;
        for (int i = ncand + tid; i < P; i += NTHR) cand[i] = 0ULL;
        __syncthreads();
        for (int size = 2; size <= P; size <<= 1) {
            for (int stride = size >> 1; stride > 0; stride >>= 1) {
                for (int i = tid; i < P; i += NTHR) {
                    int j = i ^ stride;
                    if (j > i) {
                        ull a = cand[i], b = cand[j];
                        bool up = ((i & size) == 0);
                        bool sw = up ? (a < b) : (a > b);
                        if (sw) { cand[i] = b; cand[j] = a; }
                    }
                }
                __syncthreads();
            }
        }
        for (int i = tid; i < 1024; i += NTHR)
            varr[i] = (i < ncand) ? (valOfKey((unsigned)(cand[i] >> 32)) / t) : NEG_BIG;
        __syncthreads();
    }

    const float m = varr[0];
    const float tkeyV = varr[k - 1];
    int ntop = k;
    while (ntop < ncand) {
        float vi = (ntop < 1024) ? varr[ntop]
                                 : (valOfKey((unsigned)(cand[ntop] >> 32)) / t);
        if (vi != tkeyV) break;
        ++ntop;
    }
    if (ntop > 1024) ntop = 1024;

    {
        float e = (tid < ntop) ? expf(varr[tid] - m) : 0.0f;
        Earr[tid] = e;
        sfx[tid] = e;
        if (tid == 0) { s_nkeep = 0; s_rank = 0; s_amax = 0ULL; }
        if (tid < 64) bitmap[tid] = 0;
    }
    __syncthreads();
    {
        float* A = sfx;
        float* Bf = sfx2;
        #pragma unroll
        for (int d = 1; d < 1024; d <<= 1) {
            float t0 = (tid + d < 1024) ? A[tid + d] : 0.0f;
            Bf[tid] = A[tid] + t0;
            __syncthreads();
            float* tmp = A; A = Bf; Bf = tmp;
        }
    }
    const float Zp = sfx[0];
    const float cmp = 1.0f - p;
    {
        int local = 0;
        for (int i = tid; i < ntop; i += NTHR)
            if (sfx[i] / Zp > cmp) local++;
        #pragma unroll
        for (int d = 1; d < 64; d <<= 1) local += __shfl_xor(local, d);
        if (lane == 0 && local) atomicAdd(&s_nkeep, local);
    }
    __syncthreads();
    const int nkeep = s_nkeep;
    if (tid == 0) {
        float vb = varr[nkeep - 1];
        int g0 = nkeep - 1;
        while (g0 > 0 && varr[g0 - 1] == vb) --g0;
        int g1 = nkeep;
        while (g1 < ntop && varr[g1] == vb) ++g1;
        s_g0 = g0; s_g1 = g1;
    }
    __syncthreads();
    const int g0 = s_g0, g1 = s_g1;
    const int mkeep = nkeep - g0;
    for (int i = g0 + tid; i < g1; i += NTHR) {
        unsigned gi = ~(unsigned)(cand[i] & 0xFFFFFFFFull);
        int rk = 0;
        for (int j = g0; j < g1; ++j) {
            unsigned gj = ~(unsigned)(cand[j] & 0xFFFFFFFFull);
            if (gj > gi) rk++;
        }
        flagArr[i] = (rk < mkeep) ? 1 : 0;
    }
    __syncthreads();

    const float Z2 = (nkeep < 1024) ? (Zp - sfx[nkeep]) : Zp;
    const float L = logf(Z2);

    {
        ull lm = 0ULL;
        for (int i = tid; i < g1; i += NTHR) {
            if (i < g0 || flagArr[i]) {
                unsigned lo = (unsigned)(cand[i] & 0xFFFFFFFFull);
                unsigned gidx = ~lo;
                float u = urow[gidx];
                float q = -((u >= RMAX_F) ? RMAX_LOG_F : logf(u));
                float prob = Earr[i] / Z2;
                float ratio = greedy ? prob : (prob / q);
                ull comp = ((ull)__float_as_uint(ratio) << 32) | lo;
                if (comp > lm) lm = comp;
                if (gidx < 2048) atomicOr(&bitmap[gidx >> 5], 1u << (gidx & 31));
            }
        }
        #pragma unroll
        for (int d = 1; d < 64; d <<= 1) {
            ull o = shflXor64(lm, d);
            if (o > lm) lm = o;
        }
        if (lane == 0 && lm) atomicMax(&s_amax, lm);
    }
    __syncthreads();
    const unsigned samp_lo = (unsigned)(s_amax & 0xFFFFFFFFull);
    const unsigned samp = ~samp_lo;
    for (int i = tid; i < ntop; i += NTHR)
        if ((unsigned)(cand[i] & 0xFFFFFFFFull) == samp_lo) s_vs = varr[i];
    __syncthreads();
    const float lp_s = (s_vs - m) - L;
    {
        int local = 0;
        for (int i = tid; i < nkeep; i += NTHR)
            if ((varr[i] - m) - L > lp_s) local++;
        #pragma unroll
        for (int d = 1; d < 64; d <<= 1) local += __shfl_xor(local, d);
        if (lane == 0 && local) atomicAdd(&s_rank, local);
    }
    __syncthreads();

    float* o_samp = out;
    float* o_idx  = out + B;
    float* o_lp   = out + B + (long long)B * (K + 1);
    float* o_rank = out + B + 2LL * B * (K + 1);
    const long long rowo = (long long)r * (K + 1);
    const int ntk = (nkeep < K) ? nkeep : K;

    if (tid < g1) {
        const int i = tid;
        bool kept = (i < g0) || flagArr[i];
        if (kept) {
            float v = varr[i];
            int rs, re, base;
            if (i >= g0) { rs = g0; re = g1; base = g0; }
            else {
                rs = i; while (rs > 0 && varr[rs - 1] == v) --rs;
                re = i + 1; while (re < g1 && varr[re] == v) ++re;
                base = rs;
            }
            if (base < ntk) {
                unsigned myidx = ~(unsigned)(cand[i] & 0xFFFFFFFFull);
                int cnt = 0;
                for (int j = rs; j < re; ++j) {
                    if (j == i) continue;
                    if (j >= g0 && !flagArr[j]) continue;
                    unsigned gj = ~(unsigned)(cand[j] & 0xFFFFFFFFull);
                    if (gj < myidx) cnt++;
                }
                int slot = base + cnt;
                if (slot < ntk) {
                    o_idx[rowo + 1 + slot] = (float)myidx;
                    o_lp[rowo + 1 + slot] = (v - m) - L;
                }
            }
        }
    }

    if (tid == 0) {
        o_samp[r] = (float)samp;
        o_idx[rowo] = (float)samp;
        o_lp[rowo] = lp_s;
        o_rank[r] = (float)s_rank;
        if (nkeep < K) {
            int j = 0;
            for (int c = nkeep; c < K; ++c) {
                while (bitmap[j >> 5] & (1u << (j & 31))) ++j;
                o_idx[rowo + 1 + c] = (float)j;
                o_lp[rowo + 1 + c] = NEG_BIG;
                ++j;
            }
        }
    }
}

extern "C" void kernel_launch(void* const* d_in, const int* in_sizes, int n_in,
                              void* d_out, int out_size, void* d_ws, size_t ws_size,
                              hipStream_t stream) {
    const float* logits      = (const float*)d_in[0];
    const float* temperature = (const float*)d_in[1];
    const int*   top_k       = (const int*)d_in[2];
    const float* top_p       = (const float*)d_in[3];
    const float* gumbel      = (const float*)d_in[4];
    int B = in_sizes[1];
    int V = in_sizes[0] / B;
    int K = (out_size / B - 4) / 2;

    // ws layout: [B*2 int meta][pad to 256][B*1024 ull sorted]
    size_t meta_bytes = (size_t)B * 2 * sizeof(int);
    size_t off = (meta_bytes + 255) & ~(size_t)255;
    size_t need = off + (size_t)B * SMALL * sizeof(ull);

    if (d_ws != nullptr && ws_size >= need) {
        int* ws_meta = (int*)d_ws;
        ull* ws_srt = (ull*)((char*)d_ws + off);
        sampler_front<<<B, NTHR, 0, stream>>>(logits, top_k, ws_srt, ws_meta, B, V);
        sampler_finish<<<B, NTHR, 0, stream>>>(temperature, top_p, gumbel,
                                               (float*)d_out, ws_srt, ws_meta,
                                               B, V, K);
    } else {
        sampler_mono<<<B, NTHR, 0, stream>>>(logits, temperature, top_k, top_p,
                                             gumbel, (float*)d_out, B, V, K);
    }
}